// Round 13
// baseline (1632.924 us; speedup 1.0000x reference)
//
#include <hip/hip_runtime.h>
#include <hip/hip_bf16.h>

#define EPS 1e-6f
#define SCAL 5.0f

// ---- static device scratch (zero-init BSS, graph-capture safe) ----
#define OFF_MU     0
#define OFF_LINV   1024
#define OFF_MUA    3072
#define OFF_LINVA  4096
#define OFF_HSUM   6144
#define OFF_ALPHA  6656
#define OFF_REC    23040
#define OFF_R1     294912
#define OFF_R2     (OFF_R1 + 8388608)
#define OFF_R3     (OFF_R2 + 8388608)
#define WS_TOTAL   (OFF_R3 + 16777216)

// B=64 batched staging (both streams; lifetimes verified):
#define OFF_X1     OFF_R3
#define OFF_X2     OFF_R1
#define OFF_APPH2  OFF_R2
#define OFF_PARTS  OFF_R3
#define OFF_PARTSA (OFF_R3 + 2097152)
#define OFF_C2     (OFF_R3 + 4194304)

// fp32 weight/bias offsets inside g_wt (separate array: provable no-alias ->
// s_load weight reads; this was the round-12 1.7x win)
#define W_ESW1 0
#define W_ESB1 1728
#define W_ESW2 1792
#define W_ESB2 38656
#define W_ESWP 38720
#define W_ESBP 47936
#define W_EAW1 47952
#define W_EAB1 84816
#define W_EAW2 84880
#define W_EAB2 103312
#define W_DW1  103344
#define W_DB1  130992
#define W_DW2  131056
#define W_DB2  149488
#define W_DW3  149520
#define W_DB3  150384

__device__ __attribute__((aligned(16))) float g_ws[WS_TOTAL];
__device__ __attribute__((aligned(16))) float g_wt[150400];
__device__ int g_isbf16;

__device__ __forceinline__ float selz(bool c, float v) { return c ? v : 0.f; }

// runtime-dtype external load (adaptive pattern — required: fixed-dtype builds NaN'd)
__device__ __forceinline__ float ldin(const void* p, size_t i, int bf) {
    return bf ? __bfloat162float(((const __hip_bfloat16*)p)[i])
              : ((const float*)p)[i];
}

// ---------------- block reductions (blockDim.x == 256) ----------------
__device__ __forceinline__ float block_sum(float v) {
    __shared__ float sb[8];
    for (int off = 32; off; off >>= 1) v += __shfl_down(v, off, 64);
    int lane = threadIdx.x & 63, wid = threadIdx.x >> 6;
    __syncthreads();
    if (lane == 0) sb[wid] = v;
    __syncthreads();
    float r = 0.f;
    for (int i = 0; i < 4; ++i) r += sb[i];
    return r;
}

__device__ __forceinline__ float block_max(float v) {
    __shared__ float sb[8];
    for (int off = 32; off; off >>= 1) v = fmaxf(v, __shfl_down(v, off, 64));
    int lane = threadIdx.x & 63, wid = threadIdx.x >> 6;
    __syncthreads();
    if (lane == 0) sb[wid] = v;
    __syncthreads();
    float r = -1e30f;
    for (int i = 0; i < 4; ++i) r = fmaxf(r, sb[i]);
    return r;
}

// ---------------- dtype probe + init ----------------
__global__ void detect_k(const void* x) {
    const __hip_bfloat16* p = (const __hip_bfloat16*)x;
    int lane = threadIdx.x & 63;
    float v = 0.f;
    for (int i = lane; i < 256; i += 64) {
        float a = fabsf(__bfloat162float(p[i]));
        if (!(a <= 2.0f)) v = 1.f;          // catches big AND NaN
    }
    for (int off = 32; off; off >>= 1) v += __shfl_down(v, off, 64);
    if (lane == 0) {
        g_isbf16 = (v == 0.f) ? 1 : 0;
        g_ws[OFF_REC] = 0.f;
    }
}

// ---------------- weight prep: external dtype -> fp32 into g_wt ----------------
__global__ void wconv_k(const void* p0, const void* p1, const void* p2, const void* p3,
                        const void* p4, const void* p5, const void* p6, const void* p7,
                        const void* p8, const void* p9, const void* p10, const void* p11,
                        const void* p12, const void* p13, const void* p14, const void* p15) {
    int bf = g_isbf16;
    const void* ps[16] = {p0,p1,p2,p3,p4,p5,p6,p7,p8,p9,p10,p11,p12,p13,p14,p15};
    const int sz[16] = {1728,64,36864,64,9216,16,36864,64,18432,32,27648,64,18432,32,864,3};
    int gid = blockIdx.x * 256 + threadIdx.x, stride = gridDim.x * 256;
    int off = 0;
    for (int a = 0; a < 16; ++a) {
        const void* p = ps[a];
        for (int i = gid; i < sz[a]; i += stride)
            g_wt[off + i] = ldin(p, i, bf);
        off += sz[a];
    }
}

// ---------------- conv1 both streams: stride-2 -> fp32 [64,64,64,64], relu ----
__global__ void __launch_bounds__(256)
conv_s2m2_k(const void* __restrict__ inA, const void* __restrict__ inB, int out_off) {
    int bf = g_isbf16;
    int tile = blockIdx.x & 15;
    int gb = blockIdx.x >> 4;
    int g = gb & 3, b = gb >> 2;
    const void* in = (b < 32) ? inA : inB;
    int bb = b & 31;
    int pix = tile * 256 + threadIdx.x;
    int y = pix >> 6, x = pix & 63;
    size_t inb = (size_t)bb * 3 * 16384;
    const float* W = g_wt + W_ESW1 + (size_t)(g * 16) * 27;
    float acc[16];
    #pragma unroll
    for (int o = 0; o < 16; ++o) acc[o] = g_wt[W_ESB1 + g * 16 + o];
    int iy0 = 2 * y, ix0 = 2 * x;
    bool my2 = (iy0 + 2 < 128), mx2 = (ix0 + 2 < 128);
    int iy2 = my2 ? iy0 + 2 : 127, ix2 = mx2 ? ix0 + 2 : 127;
    for (int ic = 0; ic < 3; ++ic) {
        size_t pb = inb + ic * 16384;
        float t[9];
        t[0] = ldin(in, pb + iy0 * 128 + ix0, bf);
        t[1] = ldin(in, pb + iy0 * 128 + ix0 + 1, bf);
        t[2] = selz(mx2, ldin(in, pb + iy0 * 128 + ix2, bf));
        t[3] = ldin(in, pb + (iy0 + 1) * 128 + ix0, bf);
        t[4] = ldin(in, pb + (iy0 + 1) * 128 + ix0 + 1, bf);
        t[5] = selz(mx2, ldin(in, pb + (iy0 + 1) * 128 + ix2, bf));
        t[6] = selz(my2, ldin(in, pb + iy2 * 128 + ix0, bf));
        t[7] = selz(my2, ldin(in, pb + iy2 * 128 + ix0 + 1, bf));
        t[8] = selz(my2 && mx2, ldin(in, pb + iy2 * 128 + ix2, bf));
        #pragma unroll
        for (int o = 0; o < 16; ++o) {
            const float* wr = W + (o * 3 + ic) * 9;
            float a = acc[o];
            #pragma unroll
            for (int j = 0; j < 9; ++j) a = fmaf(t[j], wr[j], a);
            acc[o] = a;
        }
    }
    float* out = g_ws + out_off + ((size_t)b * 64 + g * 16) * 4096 + pix;
    #pragma unroll
    for (int o = 0; o < 16; ++o) out[o * 4096] = fmaxf(acc[o], 0.f);
}

// ---------------- tiled 3x3 SAME conv on 64x64 planes: 1x4 px x OCG ocs per thread ----
// OCG sized so grid >= 2048 blocks (8/CU, 32 waves) for latency hiding
template<int CIN, int OCG>
__global__ void __launch_bounds__(256)
conv64t_k(int in_off, int w_off, int b_off, int out_off, int ng, int Cout, int relu) {
    int by = blockIdx.x & 3;
    int gb = blockIdx.x >> 2;
    int g = gb % ng, b = gb / ng;
    int xq = threadIdx.x & 15, ry = threadIdx.x >> 4;
    int y = by * 16 + ry, x0 = xq * 4;
    const float* inb = g_ws + in_off + (size_t)b * CIN * 4096;
    const float* W = g_wt + w_off + (size_t)(g * OCG) * CIN * 9;
    float acc[OCG][4];
    #pragma unroll
    for (int o = 0; o < OCG; ++o) {
        float bv = g_wt[b_off + g * OCG + o];
        #pragma unroll
        for (int p = 0; p < 4; ++p) acc[o][p] = bv;
    }
    bool ym = y > 0, yp = y < 63, xm = x0 > 0, xp = x0 < 60;
    int rm = (ym ? y - 1 : 0) * 64, r0 = y * 64, rp = (yp ? y + 1 : 63) * 64;
    int cxm = xm ? x0 - 1 : 0, cxp = xp ? x0 + 4 : 63;
    for (int ic = 0; ic < CIN; ++ic) {
        const float* p = inb + ic * 4096;
        float4 q0 = *(const float4*)(p + rm + x0);
        float4 q1 = *(const float4*)(p + r0 + x0);
        float4 q2 = *(const float4*)(p + rp + x0);
        float t0[6], t1[6], t2[6];
        t0[0] = selz(ym && xm, p[rm + cxm]);
        t0[1] = selz(ym, q0.x); t0[2] = selz(ym, q0.y);
        t0[3] = selz(ym, q0.z); t0[4] = selz(ym, q0.w);
        t0[5] = selz(ym && xp, p[rm + cxp]);
        t1[0] = selz(xm, p[r0 + cxm]);
        t1[1] = q1.x; t1[2] = q1.y; t1[3] = q1.z; t1[4] = q1.w;
        t1[5] = selz(xp, p[r0 + cxp]);
        t2[0] = selz(yp && xm, p[rp + cxm]);
        t2[1] = selz(yp, q2.x); t2[2] = selz(yp, q2.y);
        t2[3] = selz(yp, q2.z); t2[4] = selz(yp, q2.w);
        t2[5] = selz(yp && xp, p[rp + cxp]);
        #pragma unroll
        for (int o = 0; o < OCG; ++o) {
            const float* wr = W + (o * CIN + ic) * 9;
            #pragma unroll
            for (int px = 0; px < 4; ++px) {
                float a = acc[o][px];
                a = fmaf(t0[px], wr[0], a); a = fmaf(t0[px+1], wr[1], a); a = fmaf(t0[px+2], wr[2], a);
                a = fmaf(t1[px], wr[3], a); a = fmaf(t1[px+1], wr[4], a); a = fmaf(t1[px+2], wr[5], a);
                a = fmaf(t2[px], wr[6], a); a = fmaf(t2[px+1], wr[7], a); a = fmaf(t2[px+2], wr[8], a);
                acc[o][px] = a;
            }
        }
    }
    float* out = g_ws + out_off + ((size_t)b * Cout + g * OCG) * 4096 + y * 64 + x0;
    #pragma unroll
    for (int o = 0; o < OCG; ++o) {
        float4 v;
        if (relu) {
            v.x = fmaxf(acc[o][0], 0.f); v.y = fmaxf(acc[o][1], 0.f);
            v.z = fmaxf(acc[o][2], 0.f); v.w = fmaxf(acc[o][3], 0.f);
        } else {
            v.x = acc[o][0]; v.y = acc[o][1]; v.z = acc[o][2]; v.w = acc[o][3];
        }
        *(float4*)(out + o * 4096) = v;
    }
}

// ---------------- fused softmax+moments over all 1024 (b,k) rows ----------------
__global__ void sm_mom2_k() {
    int bk = blockIdx.x;
    int app = (bk >= 512);
    float* row = g_ws + OFF_PARTS + (size_t)bk * 4096;
    float r[16];
    #pragma unroll
    for (int j = 0; j < 16; ++j) r[j] = row[threadIdx.x + j * 256];
    float m = r[0];
    #pragma unroll
    for (int j = 1; j < 16; ++j) m = fmaxf(m, r[j]);
    m = block_max(m);
    float s = 0.f;
    #pragma unroll
    for (int j = 0; j < 16; ++j) { r[j] = __expf(r[j] - m); s += r[j]; }
    s = block_sum(s);
    float inv = 1.0f / s;
    float sy = 0, sx = 0, syy = 0, sxy = 0, sxx = 0;
    #pragma unroll
    for (int j = 0; j < 16; ++j) {
        float pv = r[j] * inv;
        int i = threadIdx.x + j * 256;
        if (app) row[i] = pv;
        float gy = -1.0f + (i >> 6) * (2.0f / 63.0f);
        float gx = -1.0f + (i & 63) * (2.0f / 63.0f);
        sy += pv * gy; sx += pv * gx;
        syy += pv * gy * gy; sxy += pv * gy * gx; sxx += pv * gx * gx;
    }
    sy = block_sum(sy); sx = block_sum(sx);
    syy = block_sum(syy); sxy = block_sum(sxy); sxx = block_sum(sxx);
    if (threadIdx.x == 0) {
        float c00 = syy - sy * sy, c01 = sxy - sy * sx, c11 = sxx - sx * sx;
        float a = sqrtf(fmaxf(c00 + EPS, 1e-12f));
        float bb = c01 / (a + EPS);
        float cc = sqrtf(fmaxf(c11 - bb * bb, 0.f) + EPS);
        float det = a * cc;
        float sc = SCAL / (det + EPS);
        int idx = app ? (bk - 512) : bk;
        int mu_off = app ? OFF_MUA : OFF_MU;
        int linv_off = app ? OFF_LINVA : OFF_LINV;
        g_ws[mu_off + idx * 2 + 0] = sy;
        g_ws[mu_off + idx * 2 + 1] = sx;
        g_ws[linv_off + idx * 4 + 0] = cc * sc;
        g_ws[linv_off + idx * 4 + 1] = 0.f;
        g_ws[linv_off + idx * 4 + 2] = -bb * sc;
        g_ws[linv_off + idx * 4 + 3] = a * sc;
    }
}

// ---------------- alpha[b,k,f] = sum_hw fxs[b,f,hw] * parts[b,k,hw] ----------------
__global__ void alpha_k(int fxs_off, int parts_off) {
    int bk = blockIdx.x;
    int b = bk >> 4;
    float* alpha = g_ws + OFF_ALPHA;
    __shared__ float pl[4096];
    const float* pr = g_ws + parts_off + (size_t)bk * 4096;
    for (int i = threadIdx.x; i < 4096; i += 256) pl[i] = pr[i];
    __syncthreads();
    const float* fb = g_ws + fxs_off + (size_t)b * 32 * 4096;
    for (int f = 0; f < 32; ++f) {
        const float* fr = fb + f * 4096;
        float s = 0.f;
        for (int i = threadIdx.x; i < 4096; i += 256) s += fr[i] * pl[i];
        s = block_sum(s);
        if (threadIdx.x == 0) alpha[bk * 32 + f] = s;
    }
}

// ---------------- heat into enc ch[0..16), plus per-(b,k) sums ----------------
__global__ void heat_k(int mu_off, int linv_off, int enc_off) {
    int bk = blockIdx.x;
    int b = bk >> 4, k = bk & 15;
    float m0 = g_ws[mu_off + bk * 2], m1 = g_ws[mu_off + bk * 2 + 1];
    float L00 = g_ws[linv_off + bk * 4 + 0], L10 = g_ws[linv_off + bk * 4 + 2],
          L11 = g_ws[linv_off + bk * 4 + 3];
    float* out = g_ws + enc_off + ((size_t)b * 48 + k) * 4096;
    float s = 0.f;
    for (int i = threadIdx.x; i < 4096; i += 256) {
        float d0 = -1.0f + (i >> 6) * (2.0f / 63.0f) - m0;
        float d1 = -1.0f + (i & 63) * (2.0f / 63.0f) - m1;
        float p0 = d0 * L00 + d1 * L10;
        float p1 = d1 * L11;
        float h = 1.0f / (1.0f + p0 * p0 + p1 * p1);
        out[i] = h;
        s += h;
    }
    s = block_sum(s);
    if (threadIdx.x == 0) g_ws[OFF_HSUM + bk] = s;
}

// ---------------- fmap into enc ch[16..48) ----------------
__global__ void fmap_k(int enc_off) {
    int t = blockIdx.x;
    int tile = t & 15, bfi = t >> 4;
    int f = bfi & 31, b = bfi >> 5;
    __shared__ float coef[16];
    if (threadIdx.x < 16) {
        int k = threadIdx.x;
        coef[k] = g_ws[OFF_ALPHA + (b * 16 + k) * 32 + f] /
                  (g_ws[OFF_HSUM + b * 16 + k] + EPS);
    }
    __syncthreads();
    int pix = tile * 256 + threadIdx.x;
    const float* hb = g_ws + enc_off + (size_t)b * 48 * 4096 + pix;
    float acc = 0.f;
    for (int k = 0; k < 16; ++k) acc += hb[k * 4096] * coef[k];
    g_ws[enc_off + ((size_t)b * 48 + 16 + f) * 4096 + pix] = acc;
}

// ---------------- tiled decoder conv2 + fused 2x nearest upsample (OCG=8) ----------------
// grid: 32b * 4g * 16by; block 256 = 8 rows x 32 xq (x0 = 4*xq)
__global__ void __launch_bounds__(256)
conv_upmt_k(int in_off, int out_off) {
    int by = blockIdx.x & 15;
    int gb = blockIdx.x >> 4;
    int g = gb & 3, b = gb >> 2;
    int xq = threadIdx.x & 31, ry = threadIdx.x >> 5;
    int y = by * 8 + ry, x0 = xq * 4;
    const float* inb = g_ws + in_off + (size_t)b * 64 * 4096;
    const float* W = g_wt + W_DW2 + (size_t)(g * 8) * 576;
    float acc[8][4];
    #pragma unroll
    for (int o = 0; o < 8; ++o) {
        float bv = g_wt[W_DB2 + g * 8 + o];
        #pragma unroll
        for (int p = 0; p < 4; ++p) acc[o][p] = bv;
    }
    int m = x0 >> 1;
    bool vxm = x0 > 0, vxp = x0 < 124;
    int c0 = vxm ? m - 1 : 0, c1 = m, c2 = m + 1, c3 = vxp ? m + 2 : 63;
    bool yv0 = y > 0, yv2 = y < 127;
    int r0 = ((yv0 ? y - 1 : 0) >> 1) * 64;
    int r1 = (y >> 1) * 64;
    int r2 = ((yv2 ? y + 1 : 127) >> 1) * 64;
    for (int ic = 0; ic < 64; ++ic) {
        const float* p = inb + ic * 4096;
        float t0[6], t1[6], t2[6];
        {
            float L0 = p[r0 + c0], L1 = p[r0 + c1], L2 = p[r0 + c2], L3 = p[r0 + c3];
            t0[0] = selz(yv0 && vxm, L0);
            t0[1] = selz(yv0, L1); t0[2] = t0[1];
            t0[3] = selz(yv0, L2); t0[4] = t0[3];
            t0[5] = selz(yv0 && vxp, L3);
        }
        {
            float L0 = p[r1 + c0], L1 = p[r1 + c1], L2 = p[r1 + c2], L3 = p[r1 + c3];
            t1[0] = selz(vxm, L0);
            t1[1] = L1; t1[2] = L1;
            t1[3] = L2; t1[4] = L2;
            t1[5] = selz(vxp, L3);
        }
        {
            float L0 = p[r2 + c0], L1 = p[r2 + c1], L2 = p[r2 + c2], L3 = p[r2 + c3];
            t2[0] = selz(yv2 && vxm, L0);
            t2[1] = selz(yv2, L1); t2[2] = t2[1];
            t2[3] = selz(yv2, L2); t2[4] = t2[3];
            t2[5] = selz(yv2 && vxp, L3);
        }
        #pragma unroll
        for (int o = 0; o < 8; ++o) {
            const float* wr = W + (o * 64 + ic) * 9;
            #pragma unroll
            for (int px = 0; px < 4; ++px) {
                float a = acc[o][px];
                a = fmaf(t0[px], wr[0], a); a = fmaf(t0[px+1], wr[1], a); a = fmaf(t0[px+2], wr[2], a);
                a = fmaf(t1[px], wr[3], a); a = fmaf(t1[px+1], wr[4], a); a = fmaf(t1[px+2], wr[5], a);
                a = fmaf(t2[px], wr[6], a); a = fmaf(t2[px+1], wr[7], a); a = fmaf(t2[px+2], wr[8], a);
                acc[o][px] = a;
            }
        }
    }
    float* out = g_ws + out_off + ((size_t)b * 32 + g * 8) * 16384 + y * 128 + x0;
    #pragma unroll
    for (int o = 0; o < 8; ++o) {
        float4 v;
        v.x = fmaxf(acc[o][0], 0.f); v.y = fmaxf(acc[o][1], 0.f);
        v.z = fmaxf(acc[o][2], 0.f); v.w = fmaxf(acc[o][3], 0.f);
        *(float4*)(out + o * 16384) = v;
    }
}

// ---------------- tiled final conv + sigmoid -> out, fused rec-loss ----------------
__global__ void __launch_bounds__(256)
conv_sigmt_k(int in_off, const void* __restrict__ ximg, void* __restrict__ outp) {
    int bf = g_isbf16;
    int by = blockIdx.x & 15;
    int b = blockIdx.x >> 4;
    int xq = threadIdx.x & 31, ry = threadIdx.x >> 5;
    int y = by * 8 + ry, x0 = xq * 4;
    const float* inb = g_ws + in_off + (size_t)b * 32 * 16384;
    const float* W = g_wt + W_DW3;
    float acc[3][4];
    #pragma unroll
    for (int o = 0; o < 3; ++o) {
        float bv = g_wt[W_DB3 + o];
        #pragma unroll
        for (int p = 0; p < 4; ++p) acc[o][p] = bv;
    }
    bool ym = y > 0, yp = y < 127, xm = x0 > 0, xp = x0 < 124;
    int rm = (ym ? y - 1 : 0) * 128, r0 = y * 128, rp = (yp ? y + 1 : 127) * 128;
    int cxm = xm ? x0 - 1 : 0, cxp = xp ? x0 + 4 : 127;
    for (int ic = 0; ic < 32; ++ic) {
        const float* p = inb + ic * 16384;
        float4 q0 = *(const float4*)(p + rm + x0);
        float4 q1 = *(const float4*)(p + r0 + x0);
        float4 q2 = *(const float4*)(p + rp + x0);
        float t0[6], t1[6], t2[6];
        t0[0] = selz(ym && xm, p[rm + cxm]);
        t0[1] = selz(ym, q0.x); t0[2] = selz(ym, q0.y);
        t0[3] = selz(ym, q0.z); t0[4] = selz(ym, q0.w);
        t0[5] = selz(ym && xp, p[rm + cxp]);
        t1[0] = selz(xm, p[r0 + cxm]);
        t1[1] = q1.x; t1[2] = q1.y; t1[3] = q1.z; t1[4] = q1.w;
        t1[5] = selz(xp, p[r0 + cxp]);
        t2[0] = selz(yp && xm, p[rp + cxm]);
        t2[1] = selz(yp, q2.x); t2[2] = selz(yp, q2.y);
        t2[3] = selz(yp, q2.z); t2[4] = selz(yp, q2.w);
        t2[5] = selz(yp && xp, p[rp + cxp]);
        #pragma unroll
        for (int o = 0; o < 3; ++o) {
            const float* wr = W + (o * 32 + ic) * 9;
            #pragma unroll
            for (int px = 0; px < 4; ++px) {
                float a = acc[o][px];
                a = fmaf(t0[px], wr[0], a); a = fmaf(t0[px+1], wr[1], a); a = fmaf(t0[px+2], wr[2], a);
                a = fmaf(t1[px], wr[3], a); a = fmaf(t1[px+1], wr[4], a); a = fmaf(t1[px+2], wr[5], a);
                a = fmaf(t2[px], wr[6], a); a = fmaf(t2[px+1], wr[7], a); a = fmaf(t2[px+2], wr[8], a);
                acc[o][px] = a;
            }
        }
    }
    float es = 0.f;
    #pragma unroll
    for (int o = 0; o < 3; ++o) {
        #pragma unroll
        for (int px = 0; px < 4; ++px) {
            float v = 1.0f / (1.0f + __expf(-acc[o][px]));
            size_t oidx = ((size_t)b * 3 + o) * 16384 + y * 128 + x0 + px;
            if (bf) ((__hip_bfloat16*)outp)[oidx] = __float2bfloat16(v);
            else    ((float*)outp)[oidx] = v;
            float e = ldin(ximg, oidx, bf) - v;
            es += e * e;
        }
    }
    float s = block_sum(es);
    if (threadIdx.x == 0) atomicAdd(&g_ws[OFF_REC], s);
}

// ---------------- scalar loss ----------------
__global__ void loss_k(const void* __restrict__ coord,
                       const void* __restrict__ vec,
                       void* __restrict__ outp) {
    int bf = g_isbf16;
    const float* mu = g_ws + OFF_MU;
    const float* linv = g_ws + OFF_LINV;
    const float* mu_a = g_ws + OFF_MUA;
    const float* linv_a = g_ws + OFF_LINVA;
    float s1 = 0, s2 = 0, s3 = 0;
    for (int i = threadIdx.x; i < 1024; i += 256) {
        float d = mu[i] - mu_a[i];
        s1 += d * d;
        float t = ldin(coord, i, bf) + ldin(vec, i, bf);
        float d3 = mu_a[i] - t;
        s3 += d3 * d3;
    }
    for (int i = threadIdx.x; i < 2048; i += 256) {
        float d = linv[i] - linv_a[i];
        s2 += d * d;
    }
    s1 = block_sum(s1);
    s2 = block_sum(s2);
    s3 = block_sum(s3);
    if (threadIdx.x == 0) {
        float loss = g_ws[OFF_REC] / 1572864.0f + s1 / 1024.0f + 0.01f * (s2 / 2048.0f)
                   + s3 / 1024.0f;
        if (bf) ((__hip_bfloat16*)outp)[1572864] = __float2bfloat16(loss);
        else    ((float*)outp)[1572864] = loss;
    }
}

extern "C" void kernel_launch(void* const* d_in, const int* in_sizes, int n_in,
                              void* d_out, int out_size, void* d_ws, size_t ws_size,
                              hipStream_t stream) {
    const void* x     = d_in[0];
    const void* x_st  = d_in[1];
    const void* x_at  = d_in[2];
    const void* coord = d_in[3];
    const void* vec   = d_in[4];

    dim3 blk(256);

    detect_k<<<1, 64, 0, stream>>>(x);
    wconv_k<<<64, blk, 0, stream>>>(
        d_in[5],  d_in[6],  d_in[7],  d_in[8],
        d_in[9],  d_in[10], d_in[11], d_in[12],
        d_in[13], d_in[14], d_in[15], d_in[16],
        d_in[17], d_in[18], d_in[19], d_in[20]);

    // ---- both encoder streams batched (B=64): conv1 -> X1(R3), conv2 -> X2(R1R2) ----
    conv_s2m2_k<<<64 * 4 * 16, blk, 0, stream>>>(x_at, x_st, OFF_X1);
    conv64t_k<64, 8><<<64 * 8 * 4, blk, 0, stream>>>(OFF_X1, W_ESW2, W_ESB2, OFF_X2, 8, 64, 1);   // 2048 blk
    conv64t_k<64, 4><<<64 * 4 * 4, blk, 0, stream>>>(OFF_X2, W_ESWP, W_ESBP, OFF_PARTS, 4, 16, 0); // 1024 blk
    sm_mom2_k<<<1024, blk, 0, stream>>>();

    // ---- e_alpha(app_sum = X2 batches 32..63 = R2) -> f_xs (C2), then alpha ----
    conv64t_k<64, 4><<<32 * 16 * 4, blk, 0, stream>>>(OFF_APPH2, W_EAW1, W_EAB1, OFF_R1, 16, 64, 1); // 2048
    conv64t_k<64, 4><<<32 * 8 * 4, blk, 0, stream>>>(OFF_R1, W_EAW2, W_EAB2, OFF_C2, 8, 32, 0);      // 1024
    alpha_k<<<512, blk, 0, stream>>>(OFF_C2, OFF_PARTSA);

    // ---- encoding into R1: heat (ch 0..15, shape mu/linv) + fmap (ch 16..47) ----
    heat_k<<<512, blk, 0, stream>>>(OFF_MU, OFF_LINV, OFF_R1);
    fmap_k<<<32 * 32 * 16, blk, 0, stream>>>(OFF_R1);

    // ---- decoder: E(R1) -> D1(R2) -> D2(R3) -> out ----
    conv64t_k<48, 4><<<32 * 16 * 4, blk, 0, stream>>>(OFF_R1, W_DW1, W_DB1, OFF_R2, 16, 64, 1);      // 2048
    conv_upmt_k<<<32 * 4 * 16, blk, 0, stream>>>(OFF_R2, OFF_R3);                                     // 2048
    conv_sigmt_k<<<32 * 16, blk, 0, stream>>>(OFF_R3, x, d_out);

    // ---- loss ----
    loss_k<<<1, blk, 0, stream>>>(coord, vec, d_out);
}

// Round 14
// 1395.535 us; speedup vs baseline: 1.1701x; 1.1701x over previous
//
#include <hip/hip_runtime.h>
#include <hip/hip_bf16.h>

#define EPS 1e-6f
#define SCAL 5.0f

// ---- static device scratch (zero-init BSS, graph-capture safe) ----
#define OFF_MU     0
#define OFF_LINV   1024
#define OFF_MUA    3072
#define OFF_LINVA  4096
#define OFF_HSUM   6144
#define OFF_ALPHA  6656
#define OFF_REC    23040
#define OFF_R1     294912
#define OFF_R2     (OFF_R1 + 8388608)
#define OFF_R3     (OFF_R2 + 8388608)
#define WS_TOTAL   (OFF_R3 + 16777216)

// B=64 batched staging (both streams; lifetimes verified):
#define OFF_X1     OFF_R3
#define OFF_X2     OFF_R1
#define OFF_APPH2  OFF_R2
#define OFF_PARTS  OFF_R3
#define OFF_PARTSA (OFF_R3 + 2097152)
#define OFF_C2     (OFF_R3 + 4194304)

// fp32 weight/bias offsets inside g_wt (separate array: provable no-alias ->
// s_load weight reads; round-12's 1.7x win)
#define W_ESW1 0
#define W_ESB1 1728
#define W_ESW2 1792
#define W_ESB2 38656
#define W_ESWP 38720
#define W_ESBP 47936
#define W_EAW1 47952
#define W_EAB1 84816
#define W_EAW2 84880
#define W_EAB2 103312
#define W_DW1  103344
#define W_DB1  130992
#define W_DW2  131056
#define W_DB2  149488
#define W_DW3  149520
#define W_DB3  150384

__device__ __attribute__((aligned(16))) float g_ws[WS_TOTAL];
__device__ __attribute__((aligned(16))) float g_wt[150400];
__device__ int g_isbf16;

__device__ __forceinline__ float selz(bool c, float v) { return c ? v : 0.f; }

// runtime-dtype external load (adaptive pattern — required: fixed-dtype builds NaN'd)
__device__ __forceinline__ float ldin(const void* p, size_t i, int bf) {
    return bf ? __bfloat162float(((const __hip_bfloat16*)p)[i])
              : ((const float*)p)[i];
}

// ---------------- block reductions (blockDim.x == 256) ----------------
__device__ __forceinline__ float block_sum(float v) {
    __shared__ float sb[8];
    for (int off = 32; off; off >>= 1) v += __shfl_down(v, off, 64);
    int lane = threadIdx.x & 63, wid = threadIdx.x >> 6;
    __syncthreads();
    if (lane == 0) sb[wid] = v;
    __syncthreads();
    float r = 0.f;
    for (int i = 0; i < 4; ++i) r += sb[i];
    return r;
}

__device__ __forceinline__ float block_max(float v) {
    __shared__ float sb[8];
    for (int off = 32; off; off >>= 1) v = fmaxf(v, __shfl_down(v, off, 64));
    int lane = threadIdx.x & 63, wid = threadIdx.x >> 6;
    __syncthreads();
    if (lane == 0) sb[wid] = v;
    __syncthreads();
    float r = -1e30f;
    for (int i = 0; i < 4; ++i) r = fmaxf(r, sb[i]);
    return r;
}

// ---------------- dtype probe + init ----------------
__global__ void detect_k(const void* x) {
    const __hip_bfloat16* p = (const __hip_bfloat16*)x;
    int lane = threadIdx.x & 63;
    float v = 0.f;
    for (int i = lane; i < 256; i += 64) {
        float a = fabsf(__bfloat162float(p[i]));
        if (!(a <= 2.0f)) v = 1.f;          // catches big AND NaN
    }
    for (int off = 32; off; off >>= 1) v += __shfl_down(v, off, 64);
    if (lane == 0) {
        g_isbf16 = (v == 0.f) ? 1 : 0;
        g_ws[OFF_REC] = 0.f;
    }
}

// ---------------- weight prep: external dtype -> fp32 into g_wt ----------------
__global__ void wconv_k(const void* p0, const void* p1, const void* p2, const void* p3,
                        const void* p4, const void* p5, const void* p6, const void* p7,
                        const void* p8, const void* p9, const void* p10, const void* p11,
                        const void* p12, const void* p13, const void* p14, const void* p15) {
    int bf = g_isbf16;
    const void* ps[16] = {p0,p1,p2,p3,p4,p5,p6,p7,p8,p9,p10,p11,p12,p13,p14,p15};
    const int sz[16] = {1728,64,36864,64,9216,16,36864,64,18432,32,27648,64,18432,32,864,3};
    int gid = blockIdx.x * 256 + threadIdx.x, stride = gridDim.x * 256;
    int off = 0;
    for (int a = 0; a < 16; ++a) {
        const void* p = ps[a];
        for (int i = gid; i < sz[a]; i += stride)
            g_wt[off + i] = ldin(p, i, bf);
        off += sz[a];
    }
}

// ---------------- conv1 both streams: stride-2 -> fp32 [64,64,64,64], relu ----
__global__ void __launch_bounds__(256)
conv_s2m2_k(const void* __restrict__ inA, const void* __restrict__ inB, int out_off) {
    int bf = g_isbf16;
    int tile = blockIdx.x & 15;
    int gb = blockIdx.x >> 4;
    int g = gb & 3, b = gb >> 2;
    const void* in = (b < 32) ? inA : inB;
    int bb = b & 31;
    int pix = tile * 256 + threadIdx.x;
    int y = pix >> 6, x = pix & 63;
    size_t inb = (size_t)bb * 3 * 16384;
    const float* W = g_wt + W_ESW1 + (size_t)(g * 16) * 27;
    float acc[16];
    #pragma unroll
    for (int o = 0; o < 16; ++o) acc[o] = g_wt[W_ESB1 + g * 16 + o];
    int iy0 = 2 * y, ix0 = 2 * x;
    bool my2 = (iy0 + 2 < 128), mx2 = (ix0 + 2 < 128);
    int iy2 = my2 ? iy0 + 2 : 127, ix2 = mx2 ? ix0 + 2 : 127;
    for (int ic = 0; ic < 3; ++ic) {
        size_t pb = inb + ic * 16384;
        float t[9];
        t[0] = ldin(in, pb + iy0 * 128 + ix0, bf);
        t[1] = ldin(in, pb + iy0 * 128 + ix0 + 1, bf);
        t[2] = selz(mx2, ldin(in, pb + iy0 * 128 + ix2, bf));
        t[3] = ldin(in, pb + (iy0 + 1) * 128 + ix0, bf);
        t[4] = ldin(in, pb + (iy0 + 1) * 128 + ix0 + 1, bf);
        t[5] = selz(mx2, ldin(in, pb + (iy0 + 1) * 128 + ix2, bf));
        t[6] = selz(my2, ldin(in, pb + iy2 * 128 + ix0, bf));
        t[7] = selz(my2, ldin(in, pb + iy2 * 128 + ix0 + 1, bf));
        t[8] = selz(my2 && mx2, ldin(in, pb + iy2 * 128 + ix2, bf));
        #pragma unroll
        for (int o = 0; o < 16; ++o) {
            const float* wr = W + (o * 3 + ic) * 9;
            float a = acc[o];
            #pragma unroll
            for (int j = 0; j < 9; ++j) a = fmaf(t[j], wr[j], a);
            acc[o] = a;
        }
    }
    float* out = g_ws + out_off + ((size_t)b * 64 + g * 16) * 4096 + pix;
    #pragma unroll
    for (int o = 0; o < 16; ++o) out[o * 4096] = fmaxf(acc[o], 0.f);
}

// ---------------- tiled 3x3 SAME conv on 64x64 planes: 1x4 px x OCG ocs per thread ----
// Software-pipelined: ic+1 taps issued before ic's FMA block (hides L2 latency).
// __launch_bounds__(256,4): VGPR budget 128 fits acc[64] + 2 tap buffers.
template<int CIN, int OCG>
__global__ void __launch_bounds__(256, 4)
conv64t_k(int in_off, int w_off, int b_off, int out_off, int ng, int Cout, int relu) {
    int by = blockIdx.x & 3;
    int gb = blockIdx.x >> 2;
    int g = gb % ng, b = gb / ng;
    int xq = threadIdx.x & 15, ry = threadIdx.x >> 4;
    int y = by * 16 + ry, x0 = xq * 4;
    const float* inb = g_ws + in_off + (size_t)b * CIN * 4096;
    const float* W = g_wt + w_off + (size_t)(g * OCG) * CIN * 9;
    float acc[OCG][4];
    #pragma unroll
    for (int o = 0; o < OCG; ++o) {
        float bv = g_wt[b_off + g * OCG + o];
        #pragma unroll
        for (int p = 0; p < 4; ++p) acc[o][p] = bv;
    }
    bool ym = y > 0, yp = y < 63, xm = x0 > 0, xp = x0 < 60;
    int rm = (ym ? y - 1 : 0) * 64, r0 = y * 64, rp = (yp ? y + 1 : 63) * 64;
    int cxm = xm ? x0 - 1 : 0, cxp = xp ? x0 + 4 : 63;
    const float* p = inb;
    // preload ic = 0
    float4 q0 = *(const float4*)(p + rm + x0);
    float4 q1 = *(const float4*)(p + r0 + x0);
    float4 q2 = *(const float4*)(p + rp + x0);
    float e0 = p[rm + cxm], e1 = p[rm + cxp];
    float e2 = p[r0 + cxm], e3 = p[r0 + cxp];
    float e4 = p[rp + cxm], e5 = p[rp + cxp];
    for (int ic = 0; ic < CIN; ++ic) {
        float4 c0 = q0, c1 = q1, c2 = q2;
        float f0 = e0, f1 = e1, f2 = e2, f3 = e3, f4 = e4, f5 = e5;
        if (ic + 1 < CIN) {                   // prefetch ic+1 while FMAs run
            p += 4096;
            q0 = *(const float4*)(p + rm + x0);
            q1 = *(const float4*)(p + r0 + x0);
            q2 = *(const float4*)(p + rp + x0);
            e0 = p[rm + cxm]; e1 = p[rm + cxp];
            e2 = p[r0 + cxm]; e3 = p[r0 + cxp];
            e4 = p[rp + cxm]; e5 = p[rp + cxp];
        }
        float t0[6], t1[6], t2[6];
        t0[0] = selz(ym && xm, f0);
        t0[1] = selz(ym, c0.x); t0[2] = selz(ym, c0.y);
        t0[3] = selz(ym, c0.z); t0[4] = selz(ym, c0.w);
        t0[5] = selz(ym && xp, f1);
        t1[0] = selz(xm, f2);
        t1[1] = c1.x; t1[2] = c1.y; t1[3] = c1.z; t1[4] = c1.w;
        t1[5] = selz(xp, f3);
        t2[0] = selz(yp && xm, f4);
        t2[1] = selz(yp, c2.x); t2[2] = selz(yp, c2.y);
        t2[3] = selz(yp, c2.z); t2[4] = selz(yp, c2.w);
        t2[5] = selz(yp && xp, f5);
        const float* wr = W + ic * 9;
        #pragma unroll
        for (int o = 0; o < OCG; ++o, wr += CIN * 9) {
            #pragma unroll
            for (int px = 0; px < 4; ++px) {
                float a = acc[o][px];
                a = fmaf(t0[px], wr[0], a); a = fmaf(t0[px+1], wr[1], a); a = fmaf(t0[px+2], wr[2], a);
                a = fmaf(t1[px], wr[3], a); a = fmaf(t1[px+1], wr[4], a); a = fmaf(t1[px+2], wr[5], a);
                a = fmaf(t2[px], wr[6], a); a = fmaf(t2[px+1], wr[7], a); a = fmaf(t2[px+2], wr[8], a);
                acc[o][px] = a;
            }
        }
    }
    float* out = g_ws + out_off + ((size_t)b * Cout + g * OCG) * 4096 + y * 64 + x0;
    #pragma unroll
    for (int o = 0; o < OCG; ++o) {
        float4 v;
        if (relu) {
            v.x = fmaxf(acc[o][0], 0.f); v.y = fmaxf(acc[o][1], 0.f);
            v.z = fmaxf(acc[o][2], 0.f); v.w = fmaxf(acc[o][3], 0.f);
        } else {
            v.x = acc[o][0]; v.y = acc[o][1]; v.z = acc[o][2]; v.w = acc[o][3];
        }
        *(float4*)(out + o * 4096) = v;
    }
}

// ---------------- fused softmax+moments over all 1024 (b,k) rows ----------------
__global__ void sm_mom2_k() {
    int bk = blockIdx.x;
    int app = (bk >= 512);
    float* row = g_ws + OFF_PARTS + (size_t)bk * 4096;
    float r[16];
    #pragma unroll
    for (int j = 0; j < 16; ++j) r[j] = row[threadIdx.x + j * 256];
    float m = r[0];
    #pragma unroll
    for (int j = 1; j < 16; ++j) m = fmaxf(m, r[j]);
    m = block_max(m);
    float s = 0.f;
    #pragma unroll
    for (int j = 0; j < 16; ++j) { r[j] = __expf(r[j] - m); s += r[j]; }
    s = block_sum(s);
    float inv = 1.0f / s;
    float sy = 0, sx = 0, syy = 0, sxy = 0, sxx = 0;
    #pragma unroll
    for (int j = 0; j < 16; ++j) {
        float pv = r[j] * inv;
        int i = threadIdx.x + j * 256;
        if (app) row[i] = pv;
        float gy = -1.0f + (i >> 6) * (2.0f / 63.0f);
        float gx = -1.0f + (i & 63) * (2.0f / 63.0f);
        sy += pv * gy; sx += pv * gx;
        syy += pv * gy * gy; sxy += pv * gy * gx; sxx += pv * gx * gx;
    }
    sy = block_sum(sy); sx = block_sum(sx);
    syy = block_sum(syy); sxy = block_sum(sxy); sxx = block_sum(sxx);
    if (threadIdx.x == 0) {
        float c00 = syy - sy * sy, c01 = sxy - sy * sx, c11 = sxx - sx * sx;
        float a = sqrtf(fmaxf(c00 + EPS, 1e-12f));
        float bb = c01 / (a + EPS);
        float cc = sqrtf(fmaxf(c11 - bb * bb, 0.f) + EPS);
        float det = a * cc;
        float sc = SCAL / (det + EPS);
        int idx = app ? (bk - 512) : bk;
        int mu_off = app ? OFF_MUA : OFF_MU;
        int linv_off = app ? OFF_LINVA : OFF_LINV;
        g_ws[mu_off + idx * 2 + 0] = sy;
        g_ws[mu_off + idx * 2 + 1] = sx;
        g_ws[linv_off + idx * 4 + 0] = cc * sc;
        g_ws[linv_off + idx * 4 + 1] = 0.f;
        g_ws[linv_off + idx * 4 + 2] = -bb * sc;
        g_ws[linv_off + idx * 4 + 3] = a * sc;
    }
}

// ---------------- alpha[b,k,f] = sum_hw fxs[b,f,hw] * parts[b,k,hw] ----------------
__global__ void alpha_k(int fxs_off, int parts_off) {
    int bk = blockIdx.x;
    int b = bk >> 4;
    float* alpha = g_ws + OFF_ALPHA;
    __shared__ float pl[4096];
    const float* pr = g_ws + parts_off + (size_t)bk * 4096;
    for (int i = threadIdx.x; i < 4096; i += 256) pl[i] = pr[i];
    __syncthreads();
    const float* fb = g_ws + fxs_off + (size_t)b * 32 * 4096;
    for (int f = 0; f < 32; ++f) {
        const float* fr = fb + f * 4096;
        float s = 0.f;
        for (int i = threadIdx.x; i < 4096; i += 256) s += fr[i] * pl[i];
        s = block_sum(s);
        if (threadIdx.x == 0) alpha[bk * 32 + f] = s;
    }
}

// ---------------- heat into enc ch[0..16), plus per-(b,k) sums ----------------
__global__ void heat_k(int mu_off, int linv_off, int enc_off) {
    int bk = blockIdx.x;
    int b = bk >> 4, k = bk & 15;
    float m0 = g_ws[mu_off + bk * 2], m1 = g_ws[mu_off + bk * 2 + 1];
    float L00 = g_ws[linv_off + bk * 4 + 0], L10 = g_ws[linv_off + bk * 4 + 2],
          L11 = g_ws[linv_off + bk * 4 + 3];
    float* out = g_ws + enc_off + ((size_t)b * 48 + k) * 4096;
    float s = 0.f;
    for (int i = threadIdx.x; i < 4096; i += 256) {
        float d0 = -1.0f + (i >> 6) * (2.0f / 63.0f) - m0;
        float d1 = -1.0f + (i & 63) * (2.0f / 63.0f) - m1;
        float p0 = d0 * L00 + d1 * L10;
        float p1 = d1 * L11;
        float h = 1.0f / (1.0f + p0 * p0 + p1 * p1);
        out[i] = h;
        s += h;
    }
    s = block_sum(s);
    if (threadIdx.x == 0) g_ws[OFF_HSUM + bk] = s;
}

// ---------------- fmap into enc ch[16..48) ----------------
__global__ void fmap_k(int enc_off) {
    int t = blockIdx.x;
    int tile = t & 15, bfi = t >> 4;
    int f = bfi & 31, b = bfi >> 5;
    __shared__ float coef[16];
    if (threadIdx.x < 16) {
        int k = threadIdx.x;
        coef[k] = g_ws[OFF_ALPHA + (b * 16 + k) * 32 + f] /
                  (g_ws[OFF_HSUM + b * 16 + k] + EPS);
    }
    __syncthreads();
    int pix = tile * 256 + threadIdx.x;
    const float* hb = g_ws + enc_off + (size_t)b * 48 * 4096 + pix;
    float acc = 0.f;
    for (int k = 0; k < 16; ++k) acc += hb[k * 4096] * coef[k];
    g_ws[enc_off + ((size_t)b * 48 + 16 + f) * 4096 + pix] = acc;
}

// ---------------- tiled decoder conv2 + fused 2x nearest upsample (OCG=16) ----------------
// Software-pipelined like conv64t. grid: 32b * 2g * 16by; block 256 = 8 rows x 32 xq
__global__ void __launch_bounds__(256, 4)
conv_upmt_k(int in_off, int out_off) {
    int by = blockIdx.x & 15;
    int gb = blockIdx.x >> 4;
    int g = gb & 1, b = gb >> 1;
    int xq = threadIdx.x & 31, ry = threadIdx.x >> 5;
    int y = by * 8 + ry, x0 = xq * 4;
    const float* inb = g_ws + in_off + (size_t)b * 64 * 4096;
    const float* W = g_wt + W_DW2 + (size_t)(g * 16) * 576;
    float acc[16][4];
    #pragma unroll
    for (int o = 0; o < 16; ++o) {
        float bv = g_wt[W_DB2 + g * 16 + o];
        #pragma unroll
        for (int p = 0; p < 4; ++p) acc[o][p] = bv;
    }
    int m = x0 >> 1;
    bool vxm = x0 > 0, vxp = x0 < 124;
    int c0i = vxm ? m - 1 : 0, c1i = m, c2i = m + 1, c3i = vxp ? m + 2 : 63;
    bool yv0 = y > 0, yv2 = y < 127;
    int r0 = ((yv0 ? y - 1 : 0) >> 1) * 64;
    int r1 = (y >> 1) * 64;
    int r2 = ((yv2 ? y + 1 : 127) >> 1) * 64;
    const float* p = inb;
    float a0 = p[r0 + c0i], a1 = p[r0 + c1i], a2 = p[r0 + c2i], a3 = p[r0 + c3i];
    float b0 = p[r1 + c0i], b1 = p[r1 + c1i], b2 = p[r1 + c2i], b3 = p[r1 + c3i];
    float d0 = p[r2 + c0i], d1 = p[r2 + c1i], d2 = p[r2 + c2i], d3 = p[r2 + c3i];
    for (int ic = 0; ic < 64; ++ic) {
        float La0 = a0, La1 = a1, La2 = a2, La3 = a3;
        float Lb0 = b0, Lb1 = b1, Lb2 = b2, Lb3 = b3;
        float Ld0 = d0, Ld1 = d1, Ld2 = d2, Ld3 = d3;
        if (ic + 1 < 64) {
            p += 4096;
            a0 = p[r0 + c0i]; a1 = p[r0 + c1i]; a2 = p[r0 + c2i]; a3 = p[r0 + c3i];
            b0 = p[r1 + c0i]; b1 = p[r1 + c1i]; b2 = p[r1 + c2i]; b3 = p[r1 + c3i];
            d0 = p[r2 + c0i]; d1 = p[r2 + c1i]; d2 = p[r2 + c2i]; d3 = p[r2 + c3i];
        }
        float t0[6], t1[6], t2[6];
        t0[0] = selz(yv0 && vxm, La0);
        t0[1] = selz(yv0, La1); t0[2] = t0[1];
        t0[3] = selz(yv0, La2); t0[4] = t0[3];
        t0[5] = selz(yv0 && vxp, La3);
        t1[0] = selz(vxm, Lb0);
        t1[1] = Lb1; t1[2] = Lb1;
        t1[3] = Lb2; t1[4] = Lb2;
        t1[5] = selz(vxp, Lb3);
        t2[0] = selz(yv2 && vxm, Ld0);
        t2[1] = selz(yv2, Ld1); t2[2] = t2[1];
        t2[3] = selz(yv2, Ld2); t2[4] = t2[3];
        t2[5] = selz(yv2 && vxp, Ld3);
        const float* wr = W + ic * 9;
        #pragma unroll
        for (int o = 0; o < 16; ++o, wr += 576) {
            #pragma unroll
            for (int px = 0; px < 4; ++px) {
                float a = acc[o][px];
                a = fmaf(t0[px], wr[0], a); a = fmaf(t0[px+1], wr[1], a); a = fmaf(t0[px+2], wr[2], a);
                a = fmaf(t1[px], wr[3], a); a = fmaf(t1[px+1], wr[4], a); a = fmaf(t1[px+2], wr[5], a);
                a = fmaf(t2[px], wr[6], a); a = fmaf(t2[px+1], wr[7], a); a = fmaf(t2[px+2], wr[8], a);
                acc[o][px] = a;
            }
        }
    }
    float* out = g_ws + out_off + ((size_t)b * 32 + g * 16) * 16384 + y * 128 + x0;
    #pragma unroll
    for (int o = 0; o < 16; ++o) {
        float4 v;
        v.x = fmaxf(acc[o][0], 0.f); v.y = fmaxf(acc[o][1], 0.f);
        v.z = fmaxf(acc[o][2], 0.f); v.w = fmaxf(acc[o][3], 0.f);
        *(float4*)(out + o * 16384) = v;
    }
}

// ---------------- tiled final conv + sigmoid -> out, fused rec-loss ----------------
__global__ void __launch_bounds__(256)
conv_sigmt_k(int in_off, const void* __restrict__ ximg, void* __restrict__ outp) {
    int bf = g_isbf16;
    int by = blockIdx.x & 15;
    int b = blockIdx.x >> 4;
    int xq = threadIdx.x & 31, ry = threadIdx.x >> 5;
    int y = by * 8 + ry, x0 = xq * 4;
    const float* inb = g_ws + in_off + (size_t)b * 32 * 16384;
    const float* W = g_wt + W_DW3;
    float acc[3][4];
    #pragma unroll
    for (int o = 0; o < 3; ++o) {
        float bv = g_wt[W_DB3 + o];
        #pragma unroll
        for (int p = 0; p < 4; ++p) acc[o][p] = bv;
    }
    bool ym = y > 0, yp = y < 127, xm = x0 > 0, xp = x0 < 124;
    int rm = (ym ? y - 1 : 0) * 128, r0 = y * 128, rp = (yp ? y + 1 : 127) * 128;
    int cxm = xm ? x0 - 1 : 0, cxp = xp ? x0 + 4 : 127;
    for (int ic = 0; ic < 32; ++ic) {
        const float* p = inb + ic * 16384;
        float4 q0 = *(const float4*)(p + rm + x0);
        float4 q1 = *(const float4*)(p + r0 + x0);
        float4 q2 = *(const float4*)(p + rp + x0);
        float t0[6], t1[6], t2[6];
        t0[0] = selz(ym && xm, p[rm + cxm]);
        t0[1] = selz(ym, q0.x); t0[2] = selz(ym, q0.y);
        t0[3] = selz(ym, q0.z); t0[4] = selz(ym, q0.w);
        t0[5] = selz(ym && xp, p[rm + cxp]);
        t1[0] = selz(xm, p[r0 + cxm]);
        t1[1] = q1.x; t1[2] = q1.y; t1[3] = q1.z; t1[4] = q1.w;
        t1[5] = selz(xp, p[r0 + cxp]);
        t2[0] = selz(yp && xm, p[rp + cxm]);
        t2[1] = selz(yp, q2.x); t2[2] = selz(yp, q2.y);
        t2[3] = selz(yp, q2.z); t2[4] = selz(yp, q2.w);
        t2[5] = selz(yp && xp, p[rp + cxp]);
        #pragma unroll
        for (int o = 0; o < 3; ++o) {
            const float* wr = W + (o * 32 + ic) * 9;
            #pragma unroll
            for (int px = 0; px < 4; ++px) {
                float a = acc[o][px];
                a = fmaf(t0[px], wr[0], a); a = fmaf(t0[px+1], wr[1], a); a = fmaf(t0[px+2], wr[2], a);
                a = fmaf(t1[px], wr[3], a); a = fmaf(t1[px+1], wr[4], a); a = fmaf(t1[px+2], wr[5], a);
                a = fmaf(t2[px], wr[6], a); a = fmaf(t2[px+1], wr[7], a); a = fmaf(t2[px+2], wr[8], a);
                acc[o][px] = a;
            }
        }
    }
    float es = 0.f;
    #pragma unroll
    for (int o = 0; o < 3; ++o) {
        #pragma unroll
        for (int px = 0; px < 4; ++px) {
            float v = 1.0f / (1.0f + __expf(-acc[o][px]));
            size_t oidx = ((size_t)b * 3 + o) * 16384 + y * 128 + x0 + px;
            if (bf) ((__hip_bfloat16*)outp)[oidx] = __float2bfloat16(v);
            else    ((float*)outp)[oidx] = v;
            float e = ldin(ximg, oidx, bf) - v;
            es += e * e;
        }
    }
    float s = block_sum(es);
    if (threadIdx.x == 0) atomicAdd(&g_ws[OFF_REC], s);
}

// ---------------- scalar loss ----------------
__global__ void loss_k(const void* __restrict__ coord,
                       const void* __restrict__ vec,
                       void* __restrict__ outp) {
    int bf = g_isbf16;
    const float* mu = g_ws + OFF_MU;
    const float* linv = g_ws + OFF_LINV;
    const float* mu_a = g_ws + OFF_MUA;
    const float* linv_a = g_ws + OFF_LINVA;
    float s1 = 0, s2 = 0, s3 = 0;
    for (int i = threadIdx.x; i < 1024; i += 256) {
        float d = mu[i] - mu_a[i];
        s1 += d * d;
        float t = ldin(coord, i, bf) + ldin(vec, i, bf);
        float d3 = mu_a[i] - t;
        s3 += d3 * d3;
    }
    for (int i = threadIdx.x; i < 2048; i += 256) {
        float d = linv[i] - linv_a[i];
        s2 += d * d;
    }
    s1 = block_sum(s1);
    s2 = block_sum(s2);
    s3 = block_sum(s3);
    if (threadIdx.x == 0) {
        float loss = g_ws[OFF_REC] / 1572864.0f + s1 / 1024.0f + 0.01f * (s2 / 2048.0f)
                   + s3 / 1024.0f;
        if (bf) ((__hip_bfloat16*)outp)[1572864] = __float2bfloat16(loss);
        else    ((float*)outp)[1572864] = loss;
    }
}

extern "C" void kernel_launch(void* const* d_in, const int* in_sizes, int n_in,
                              void* d_out, int out_size, void* d_ws, size_t ws_size,
                              hipStream_t stream) {
    const void* x     = d_in[0];
    const void* x_st  = d_in[1];
    const void* x_at  = d_in[2];
    const void* coord = d_in[3];
    const void* vec   = d_in[4];

    dim3 blk(256);

    detect_k<<<1, 64, 0, stream>>>(x);
    wconv_k<<<64, blk, 0, stream>>>(
        d_in[5],  d_in[6],  d_in[7],  d_in[8],
        d_in[9],  d_in[10], d_in[11], d_in[12],
        d_in[13], d_in[14], d_in[15], d_in[16],
        d_in[17], d_in[18], d_in[19], d_in[20]);

    // ---- round-12 launch shapes (OCG=16/8): issue-mix > occupancy (round-13 lesson) ----
    conv_s2m2_k<<<64 * 4 * 16, blk, 0, stream>>>(x_at, x_st, OFF_X1);
    conv64t_k<64, 16><<<64 * 4 * 4, blk, 0, stream>>>(OFF_X1, W_ESW2, W_ESB2, OFF_X2, 4, 64, 1);
    conv64t_k<64, 8><<<64 * 2 * 4, blk, 0, stream>>>(OFF_X2, W_ESWP, W_ESBP, OFF_PARTS, 2, 16, 0);
    sm_mom2_k<<<1024, blk, 0, stream>>>();

    // ---- e_alpha(app_sum = X2 batches 32..63 = R2) -> f_xs (C2), then alpha ----
    conv64t_k<64, 8><<<32 * 8 * 4, blk, 0, stream>>>(OFF_APPH2, W_EAW1, W_EAB1, OFF_R1, 8, 64, 1);
    conv64t_k<64, 8><<<32 * 4 * 4, blk, 0, stream>>>(OFF_R1, W_EAW2, W_EAB2, OFF_C2, 4, 32, 0);
    alpha_k<<<512, blk, 0, stream>>>(OFF_C2, OFF_PARTSA);

    // ---- encoding into R1: heat (ch 0..15, shape mu/linv) + fmap (ch 16..47) ----
    heat_k<<<512, blk, 0, stream>>>(OFF_MU, OFF_LINV, OFF_R1);
    fmap_k<<<32 * 32 * 16, blk, 0, stream>>>(OFF_R1);

    // ---- decoder: E(R1) -> D1(R2) -> D2(R3) -> out ----
    conv64t_k<48, 8><<<32 * 8 * 4, blk, 0, stream>>>(OFF_R1, W_DW1, W_DB1, OFF_R2, 8, 64, 1);
    conv_upmt_k<<<32 * 2 * 16, blk, 0, stream>>>(OFF_R2, OFF_R3);
    conv_sigmt_k<<<32 * 16, blk, 0, stream>>>(OFF_R3, x, d_out);

    // ---- loss ----
    loss_k<<<1, blk, 0, stream>>>(coord, vec, d_out);
}

// Round 15
// 1187.954 us; speedup vs baseline: 1.3746x; 1.1747x over previous
//
#include <hip/hip_runtime.h>
#include <hip/hip_bf16.h>

#define EPS 1e-6f
#define SCAL 5.0f

// ---- static device scratch (zero-init BSS, graph-capture safe) ----
#define OFF_MU     0
#define OFF_LINV   1024
#define OFF_MUA    3072
#define OFF_LINVA  4096
#define OFF_HSUM   6144
#define OFF_ALPHA  6656
#define OFF_REC    23040
#define OFF_R1     294912
#define OFF_R2     (OFF_R1 + 8388608)
#define OFF_R3     (OFF_R2 + 8388608)
#define WS_TOTAL   (OFF_R3 + 16777216)

// B=64 batched staging (both streams; lifetimes verified):
#define OFF_X1     OFF_R3
#define OFF_X2     OFF_R1
#define OFF_APPH2  OFF_R2
#define OFF_PARTS  OFF_R3
#define OFF_PARTSA (OFF_R3 + 2097152)
#define OFF_C2     (OFF_R3 + 4194304)

// fp32 weight/bias offsets inside g_wt (separate array: provable no-alias ->
// s_load weight reads; round-12's 1.7x win)
#define W_ESW1 0
#define W_ESB1 1728
#define W_ESW2 1792
#define W_ESB2 38656
#define W_ESWP 38720
#define W_ESBP 47936
#define W_EAW1 47952
#define W_EAB1 84816
#define W_EAW2 84880
#define W_EAB2 103312
#define W_DW1  103344
#define W_DB1  130992
#define W_DW2  131056
#define W_DB2  149488
#define W_DW3  149520
#define W_DB3  150384

__device__ __attribute__((aligned(16))) float g_ws[WS_TOTAL];
__device__ __attribute__((aligned(16))) float g_wt[150400];
__device__ int g_isbf16;

__device__ __forceinline__ float selz(bool c, float v) { return c ? v : 0.f; }

// runtime-dtype external load (adaptive pattern — required: fixed-dtype builds NaN'd)
__device__ __forceinline__ float ldin(const void* p, size_t i, int bf) {
    return bf ? __bfloat162float(((const __hip_bfloat16*)p)[i])
              : ((const float*)p)[i];
}

// ---------------- block reductions (blockDim.x == 256) ----------------
__device__ __forceinline__ float block_sum(float v) {
    __shared__ float sb[8];
    for (int off = 32; off; off >>= 1) v += __shfl_down(v, off, 64);
    int lane = threadIdx.x & 63, wid = threadIdx.x >> 6;
    __syncthreads();
    if (lane == 0) sb[wid] = v;
    __syncthreads();
    float r = 0.f;
    for (int i = 0; i < 4; ++i) r += sb[i];
    return r;
}

__device__ __forceinline__ float block_max(float v) {
    __shared__ float sb[8];
    for (int off = 32; off; off >>= 1) v = fmaxf(v, __shfl_down(v, off, 64));
    int lane = threadIdx.x & 63, wid = threadIdx.x >> 6;
    __syncthreads();
    if (lane == 0) sb[wid] = v;
    __syncthreads();
    float r = -1e30f;
    for (int i = 0; i < 4; ++i) r = fmaxf(r, sb[i]);
    return r;
}

// ---------------- dtype probe + init ----------------
__global__ void detect_k(const void* x) {
    const __hip_bfloat16* p = (const __hip_bfloat16*)x;
    int lane = threadIdx.x & 63;
    float v = 0.f;
    for (int i = lane; i < 256; i += 64) {
        float a = fabsf(__bfloat162float(p[i]));
        if (!(a <= 2.0f)) v = 1.f;          // catches big AND NaN
    }
    for (int off = 32; off; off >>= 1) v += __shfl_down(v, off, 64);
    if (lane == 0) {
        g_isbf16 = (v == 0.f) ? 1 : 0;
        g_ws[OFF_REC] = 0.f;
    }
}

// ---------------- weight prep: external dtype -> fp32 into g_wt ----------------
__global__ void wconv_k(const void* p0, const void* p1, const void* p2, const void* p3,
                        const void* p4, const void* p5, const void* p6, const void* p7,
                        const void* p8, const void* p9, const void* p10, const void* p11,
                        const void* p12, const void* p13, const void* p14, const void* p15) {
    int bf = g_isbf16;
    const void* ps[16] = {p0,p1,p2,p3,p4,p5,p6,p7,p8,p9,p10,p11,p12,p13,p14,p15};
    const int sz[16] = {1728,64,36864,64,9216,16,36864,64,18432,32,27648,64,18432,32,864,3};
    int gid = blockIdx.x * 256 + threadIdx.x, stride = gridDim.x * 256;
    int off = 0;
    for (int a = 0; a < 16; ++a) {
        const void* p = ps[a];
        for (int i = gid; i < sz[a]; i += stride)
            g_wt[off + i] = ldin(p, i, bf);
        off += sz[a];
    }
}

// ---------------- conv1 both streams: stride-2 -> fp32 [64,64,64,64], relu ----
__global__ void __launch_bounds__(256)
conv_s2m2_k(const void* __restrict__ inA, const void* __restrict__ inB, int out_off) {
    int bf = g_isbf16;
    int tile = blockIdx.x & 15;
    int gb = blockIdx.x >> 4;
    int g = gb & 3, b = gb >> 2;
    const void* in = (b < 32) ? inA : inB;
    int bb = b & 31;
    int pix = tile * 256 + threadIdx.x;
    int y = pix >> 6, x = pix & 63;
    size_t inb = (size_t)bb * 3 * 16384;
    const float* W = g_wt + W_ESW1 + (size_t)(g * 16) * 27;
    float acc[16];
    #pragma unroll
    for (int o = 0; o < 16; ++o) acc[o] = g_wt[W_ESB1 + g * 16 + o];
    int iy0 = 2 * y, ix0 = 2 * x;
    bool my2 = (iy0 + 2 < 128), mx2 = (ix0 + 2 < 128);
    int iy2 = my2 ? iy0 + 2 : 127, ix2 = mx2 ? ix0 + 2 : 127;
    for (int ic = 0; ic < 3; ++ic) {
        size_t pb = inb + ic * 16384;
        float t[9];
        t[0] = ldin(in, pb + iy0 * 128 + ix0, bf);
        t[1] = ldin(in, pb + iy0 * 128 + ix0 + 1, bf);
        t[2] = selz(mx2, ldin(in, pb + iy0 * 128 + ix2, bf));
        t[3] = ldin(in, pb + (iy0 + 1) * 128 + ix0, bf);
        t[4] = ldin(in, pb + (iy0 + 1) * 128 + ix0 + 1, bf);
        t[5] = selz(mx2, ldin(in, pb + (iy0 + 1) * 128 + ix2, bf));
        t[6] = selz(my2, ldin(in, pb + iy2 * 128 + ix0, bf));
        t[7] = selz(my2, ldin(in, pb + iy2 * 128 + ix0 + 1, bf));
        t[8] = selz(my2 && mx2, ldin(in, pb + iy2 * 128 + ix2, bf));
        #pragma unroll
        for (int o = 0; o < 16; ++o) {
            const float* wr = W + (o * 3 + ic) * 9;
            float a = acc[o];
            #pragma unroll
            for (int j = 0; j < 9; ++j) a = fmaf(t[j], wr[j], a);
            acc[o] = a;
        }
    }
    float* out = g_ws + out_off + ((size_t)b * 64 + g * 16) * 4096 + pix;
    #pragma unroll
    for (int o = 0; o < 16; ++o) out[o * 4096] = fmaxf(acc[o], 0.f);
}

// ---------------- tiled 3x3 SAME conv on 64x64 planes: 1x4 px x OCG ocs per thread ----
// amdgpu_waves_per_eu(2,4): lets the allocator use up to 256 VGPRs instead of
// clamping to 64 and spilling (round-14 diagnosis: WRITE_SIZE 296MB of scratch)
template<int CIN, int OCG>
__global__ void __launch_bounds__(256) __attribute__((amdgpu_waves_per_eu(2, 4)))
conv64t_k(int in_off, int w_off, int b_off, int out_off, int ng, int Cout, int relu) {
    int by = blockIdx.x & 3;
    int gb = blockIdx.x >> 2;
    int g = gb % ng, b = gb / ng;
    int xq = threadIdx.x & 15, ry = threadIdx.x >> 4;
    int y = by * 16 + ry, x0 = xq * 4;
    const float* inb = g_ws + in_off + (size_t)b * CIN * 4096;
    const float* W = g_wt + w_off + (size_t)(g * OCG) * CIN * 9;
    float acc[OCG][4];
    #pragma unroll
    for (int o = 0; o < OCG; ++o) {
        float bv = g_wt[b_off + g * OCG + o];
        #pragma unroll
        for (int p = 0; p < 4; ++p) acc[o][p] = bv;
    }
    bool ym = y > 0, yp = y < 63, xm = x0 > 0, xp = x0 < 60;
    int rm = (ym ? y - 1 : 0) * 64, r0 = y * 64, rp = (yp ? y + 1 : 63) * 64;
    int cxm = xm ? x0 - 1 : 0, cxp = xp ? x0 + 4 : 63;
    for (int ic = 0; ic < CIN; ++ic) {
        const float* p = inb + ic * 4096;
        float4 q0 = *(const float4*)(p + rm + x0);
        float4 q1 = *(const float4*)(p + r0 + x0);
        float4 q2 = *(const float4*)(p + rp + x0);
        float t0[6], t1[6], t2[6];
        t0[0] = selz(ym && xm, p[rm + cxm]);
        t0[1] = selz(ym, q0.x); t0[2] = selz(ym, q0.y);
        t0[3] = selz(ym, q0.z); t0[4] = selz(ym, q0.w);
        t0[5] = selz(ym && xp, p[rm + cxp]);
        t1[0] = selz(xm, p[r0 + cxm]);
        t1[1] = q1.x; t1[2] = q1.y; t1[3] = q1.z; t1[4] = q1.w;
        t1[5] = selz(xp, p[r0 + cxp]);
        t2[0] = selz(yp && xm, p[rp + cxm]);
        t2[1] = selz(yp, q2.x); t2[2] = selz(yp, q2.y);
        t2[3] = selz(yp, q2.z); t2[4] = selz(yp, q2.w);
        t2[5] = selz(yp && xp, p[rp + cxp]);
        #pragma unroll
        for (int o = 0; o < OCG; ++o) {
            const float* wr = W + (o * CIN + ic) * 9;
            #pragma unroll
            for (int px = 0; px < 4; ++px) {
                float a = acc[o][px];
                a = fmaf(t0[px], wr[0], a); a = fmaf(t0[px+1], wr[1], a); a = fmaf(t0[px+2], wr[2], a);
                a = fmaf(t1[px], wr[3], a); a = fmaf(t1[px+1], wr[4], a); a = fmaf(t1[px+2], wr[5], a);
                a = fmaf(t2[px], wr[6], a); a = fmaf(t2[px+1], wr[7], a); a = fmaf(t2[px+2], wr[8], a);
                acc[o][px] = a;
            }
        }
    }
    float* out = g_ws + out_off + ((size_t)b * Cout + g * OCG) * 4096 + y * 64 + x0;
    #pragma unroll
    for (int o = 0; o < OCG; ++o) {
        float4 v;
        if (relu) {
            v.x = fmaxf(acc[o][0], 0.f); v.y = fmaxf(acc[o][1], 0.f);
            v.z = fmaxf(acc[o][2], 0.f); v.w = fmaxf(acc[o][3], 0.f);
        } else {
            v.x = acc[o][0]; v.y = acc[o][1]; v.z = acc[o][2]; v.w = acc[o][3];
        }
        *(float4*)(out + o * 4096) = v;
    }
}

// ---------------- fused softmax+moments over all 1024 (b,k) rows ----------------
__global__ void sm_mom2_k() {
    int bk = blockIdx.x;
    int app = (bk >= 512);
    float* row = g_ws + OFF_PARTS + (size_t)bk * 4096;
    float r[16];
    #pragma unroll
    for (int j = 0; j < 16; ++j) r[j] = row[threadIdx.x + j * 256];
    float m = r[0];
    #pragma unroll
    for (int j = 1; j < 16; ++j) m = fmaxf(m, r[j]);
    m = block_max(m);
    float s = 0.f;
    #pragma unroll
    for (int j = 0; j < 16; ++j) { r[j] = __expf(r[j] - m); s += r[j]; }
    s = block_sum(s);
    float inv = 1.0f / s;
    float sy = 0, sx = 0, syy = 0, sxy = 0, sxx = 0;
    #pragma unroll
    for (int j = 0; j < 16; ++j) {
        float pv = r[j] * inv;
        int i = threadIdx.x + j * 256;
        if (app) row[i] = pv;
        float gy = -1.0f + (i >> 6) * (2.0f / 63.0f);
        float gx = -1.0f + (i & 63) * (2.0f / 63.0f);
        sy += pv * gy; sx += pv * gx;
        syy += pv * gy * gy; sxy += pv * gy * gx; sxx += pv * gx * gx;
    }
    sy = block_sum(sy); sx = block_sum(sx);
    syy = block_sum(syy); sxy = block_sum(sxy); sxx = block_sum(sxx);
    if (threadIdx.x == 0) {
        float c00 = syy - sy * sy, c01 = sxy - sy * sx, c11 = sxx - sx * sx;
        float a = sqrtf(fmaxf(c00 + EPS, 1e-12f));
        float bb = c01 / (a + EPS);
        float cc = sqrtf(fmaxf(c11 - bb * bb, 0.f) + EPS);
        float det = a * cc;
        float sc = SCAL / (det + EPS);
        int idx = app ? (bk - 512) : bk;
        int mu_off = app ? OFF_MUA : OFF_MU;
        int linv_off = app ? OFF_LINVA : OFF_LINV;
        g_ws[mu_off + idx * 2 + 0] = sy;
        g_ws[mu_off + idx * 2 + 1] = sx;
        g_ws[linv_off + idx * 4 + 0] = cc * sc;
        g_ws[linv_off + idx * 4 + 1] = 0.f;
        g_ws[linv_off + idx * 4 + 2] = -bb * sc;
        g_ws[linv_off + idx * 4 + 3] = a * sc;
    }
}

// ---------------- alpha[b,k,f] = sum_hw fxs[b,f,hw] * parts[b,k,hw] ----------------
__global__ void alpha_k(int fxs_off, int parts_off) {
    int bk = blockIdx.x;
    int b = bk >> 4;
    float* alpha = g_ws + OFF_ALPHA;
    __shared__ float pl[4096];
    const float* pr = g_ws + parts_off + (size_t)bk * 4096;
    for (int i = threadIdx.x; i < 4096; i += 256) pl[i] = pr[i];
    __syncthreads();
    const float* fb = g_ws + fxs_off + (size_t)b * 32 * 4096;
    for (int f = 0; f < 32; ++f) {
        const float* fr = fb + f * 4096;
        float s = 0.f;
        for (int i = threadIdx.x; i < 4096; i += 256) s += fr[i] * pl[i];
        s = block_sum(s);
        if (threadIdx.x == 0) alpha[bk * 32 + f] = s;
    }
}

// ---------------- heat into enc ch[0..16), plus per-(b,k) sums ----------------
__global__ void heat_k(int mu_off, int linv_off, int enc_off) {
    int bk = blockIdx.x;
    int b = bk >> 4, k = bk & 15;
    float m0 = g_ws[mu_off + bk * 2], m1 = g_ws[mu_off + bk * 2 + 1];
    float L00 = g_ws[linv_off + bk * 4 + 0], L10 = g_ws[linv_off + bk * 4 + 2],
          L11 = g_ws[linv_off + bk * 4 + 3];
    float* out = g_ws + enc_off + ((size_t)b * 48 + k) * 4096;
    float s = 0.f;
    for (int i = threadIdx.x; i < 4096; i += 256) {
        float d0 = -1.0f + (i >> 6) * (2.0f / 63.0f) - m0;
        float d1 = -1.0f + (i & 63) * (2.0f / 63.0f) - m1;
        float p0 = d0 * L00 + d1 * L10;
        float p1 = d1 * L11;
        float h = 1.0f / (1.0f + p0 * p0 + p1 * p1);
        out[i] = h;
        s += h;
    }
    s = block_sum(s);
    if (threadIdx.x == 0) g_ws[OFF_HSUM + bk] = s;
}

// ---------------- fmap into enc ch[16..48) ----------------
__global__ void fmap_k(int enc_off) {
    int t = blockIdx.x;
    int tile = t & 15, bfi = t >> 4;
    int f = bfi & 31, b = bfi >> 5;
    __shared__ float coef[16];
    if (threadIdx.x < 16) {
        int k = threadIdx.x;
        coef[k] = g_ws[OFF_ALPHA + (b * 16 + k) * 32 + f] /
                  (g_ws[OFF_HSUM + b * 16 + k] + EPS);
    }
    __syncthreads();
    int pix = tile * 256 + threadIdx.x;
    const float* hb = g_ws + enc_off + (size_t)b * 48 * 4096 + pix;
    float acc = 0.f;
    for (int k = 0; k < 16; ++k) acc += hb[k * 4096] * coef[k];
    g_ws[enc_off + ((size_t)b * 48 + 16 + f) * 4096 + pix] = acc;
}

// ---------------- tiled decoder conv2 + fused 2x nearest upsample (OCG=16) ----------------
// grid: 32b * 2g * 16by; block 256 = 8 rows x 32 xq (x0 = 4*xq)
__global__ void __launch_bounds__(256) __attribute__((amdgpu_waves_per_eu(2, 4)))
conv_upmt_k(int in_off, int out_off) {
    int by = blockIdx.x & 15;
    int gb = blockIdx.x >> 4;
    int g = gb & 1, b = gb >> 1;
    int xq = threadIdx.x & 31, ry = threadIdx.x >> 5;
    int y = by * 8 + ry, x0 = xq * 4;
    const float* inb = g_ws + in_off + (size_t)b * 64 * 4096;
    const float* W = g_wt + W_DW2 + (size_t)(g * 16) * 576;
    float acc[16][4];
    #pragma unroll
    for (int o = 0; o < 16; ++o) {
        float bv = g_wt[W_DB2 + g * 16 + o];
        #pragma unroll
        for (int p = 0; p < 4; ++p) acc[o][p] = bv;
    }
    int m = x0 >> 1;
    bool vxm = x0 > 0, vxp = x0 < 124;
    int c0 = vxm ? m - 1 : 0, c1 = m, c2 = m + 1, c3 = vxp ? m + 2 : 63;
    bool yv0 = y > 0, yv2 = y < 127;
    int r0 = ((yv0 ? y - 1 : 0) >> 1) * 64;
    int r1 = (y >> 1) * 64;
    int r2 = ((yv2 ? y + 1 : 127) >> 1) * 64;
    for (int ic = 0; ic < 64; ++ic) {
        const float* p = inb + ic * 4096;
        float t0[6], t1[6], t2[6];
        {
            float L0 = p[r0 + c0], L1 = p[r0 + c1], L2 = p[r0 + c2], L3 = p[r0 + c3];
            t0[0] = selz(yv0 && vxm, L0);
            t0[1] = selz(yv0, L1); t0[2] = t0[1];
            t0[3] = selz(yv0, L2); t0[4] = t0[3];
            t0[5] = selz(yv0 && vxp, L3);
        }
        {
            float L0 = p[r1 + c0], L1 = p[r1 + c1], L2 = p[r1 + c2], L3 = p[r1 + c3];
            t1[0] = selz(vxm, L0);
            t1[1] = L1; t1[2] = L1;
            t1[3] = L2; t1[4] = L2;
            t1[5] = selz(vxp, L3);
        }
        {
            float L0 = p[r2 + c0], L1 = p[r2 + c1], L2 = p[r2 + c2], L3 = p[r2 + c3];
            t2[0] = selz(yv2 && vxm, L0);
            t2[1] = selz(yv2, L1); t2[2] = t2[1];
            t2[3] = selz(yv2, L2); t2[4] = t2[3];
            t2[5] = selz(yv2 && vxp, L3);
        }
        #pragma unroll
        for (int o = 0; o < 16; ++o) {
            const float* wr = W + (o * 64 + ic) * 9;
            #pragma unroll
            for (int px = 0; px < 4; ++px) {
                float a = acc[o][px];
                a = fmaf(t0[px], wr[0], a); a = fmaf(t0[px+1], wr[1], a); a = fmaf(t0[px+2], wr[2], a);
                a = fmaf(t1[px], wr[3], a); a = fmaf(t1[px+1], wr[4], a); a = fmaf(t1[px+2], wr[5], a);
                a = fmaf(t2[px], wr[6], a); a = fmaf(t2[px+1], wr[7], a); a = fmaf(t2[px+2], wr[8], a);
                acc[o][px] = a;
            }
        }
    }
    float* out = g_ws + out_off + ((size_t)b * 32 + g * 16) * 16384 + y * 128 + x0;
    #pragma unroll
    for (int o = 0; o < 16; ++o) {
        float4 v;
        v.x = fmaxf(acc[o][0], 0.f); v.y = fmaxf(acc[o][1], 0.f);
        v.z = fmaxf(acc[o][2], 0.f); v.w = fmaxf(acc[o][3], 0.f);
        *(float4*)(out + o * 16384) = v;
    }
}

// ---------------- tiled final conv + sigmoid -> out, fused rec-loss ----------------
__global__ void __launch_bounds__(256)
conv_sigmt_k(int in_off, const void* __restrict__ ximg, void* __restrict__ outp) {
    int bf = g_isbf16;
    int by = blockIdx.x & 15;
    int b = blockIdx.x >> 4;
    int xq = threadIdx.x & 31, ry = threadIdx.x >> 5;
    int y = by * 8 + ry, x0 = xq * 4;
    const float* inb = g_ws + in_off + (size_t)b * 32 * 16384;
    const float* W = g_wt + W_DW3;
    float acc[3][4];
    #pragma unroll
    for (int o = 0; o < 3; ++o) {
        float bv = g_wt[W_DB3 + o];
        #pragma unroll
        for (int p = 0; p < 4; ++p) acc[o][p] = bv;
    }
    bool ym = y > 0, yp = y < 127, xm = x0 > 0, xp = x0 < 124;
    int rm = (ym ? y - 1 : 0) * 128, r0 = y * 128, rp = (yp ? y + 1 : 127) * 128;
    int cxm = xm ? x0 - 1 : 0, cxp = xp ? x0 + 4 : 127;
    for (int ic = 0; ic < 32; ++ic) {
        const float* p = inb + ic * 16384;
        float4 q0 = *(const float4*)(p + rm + x0);
        float4 q1 = *(const float4*)(p + r0 + x0);
        float4 q2 = *(const float4*)(p + rp + x0);
        float t0[6], t1[6], t2[6];
        t0[0] = selz(ym && xm, p[rm + cxm]);
        t0[1] = selz(ym, q0.x); t0[2] = selz(ym, q0.y);
        t0[3] = selz(ym, q0.z); t0[4] = selz(ym, q0.w);
        t0[5] = selz(ym && xp, p[rm + cxp]);
        t1[0] = selz(xm, p[r0 + cxm]);
        t1[1] = q1.x; t1[2] = q1.y; t1[3] = q1.z; t1[4] = q1.w;
        t1[5] = selz(xp, p[r0 + cxp]);
        t2[0] = selz(yp && xm, p[rp + cxm]);
        t2[1] = selz(yp, q2.x); t2[2] = selz(yp, q2.y);
        t2[3] = selz(yp, q2.z); t2[4] = selz(yp, q2.w);
        t2[5] = selz(yp && xp, p[rp + cxp]);
        #pragma unroll
        for (int o = 0; o < 3; ++o) {
            const float* wr = W + (o * 32 + ic) * 9;
            #pragma unroll
            for (int px = 0; px < 4; ++px) {
                float a = acc[o][px];
                a = fmaf(t0[px], wr[0], a); a = fmaf(t0[px+1], wr[1], a); a = fmaf(t0[px+2], wr[2], a);
                a = fmaf(t1[px], wr[3], a); a = fmaf(t1[px+1], wr[4], a); a = fmaf(t1[px+2], wr[5], a);
                a = fmaf(t2[px], wr[6], a); a = fmaf(t2[px+1], wr[7], a); a = fmaf(t2[px+2], wr[8], a);
                acc[o][px] = a;
            }
        }
    }
    float es = 0.f;
    #pragma unroll
    for (int o = 0; o < 3; ++o) {
        #pragma unroll
        for (int px = 0; px < 4; ++px) {
            float v = 1.0f / (1.0f + __expf(-acc[o][px]));
            size_t oidx = ((size_t)b * 3 + o) * 16384 + y * 128 + x0 + px;
            if (bf) ((__hip_bfloat16*)outp)[oidx] = __float2bfloat16(v);
            else    ((float*)outp)[oidx] = v;
            float e = ldin(ximg, oidx, bf) - v;
            es += e * e;
        }
    }
    float s = block_sum(es);
    if (threadIdx.x == 0) atomicAdd(&g_ws[OFF_REC], s);
}

// ---------------- scalar loss ----------------
__global__ void loss_k(const void* __restrict__ coord,
                       const void* __restrict__ vec,
                       void* __restrict__ outp) {
    int bf = g_isbf16;
    const float* mu = g_ws + OFF_MU;
    const float* linv = g_ws + OFF_LINV;
    const float* mu_a = g_ws + OFF_MUA;
    const float* linv_a = g_ws + OFF_LINVA;
    float s1 = 0, s2 = 0, s3 = 0;
    for (int i = threadIdx.x; i < 1024; i += 256) {
        float d = mu[i] - mu_a[i];
        s1 += d * d;
        float t = ldin(coord, i, bf) + ldin(vec, i, bf);
        float d3 = mu_a[i] - t;
        s3 += d3 * d3;
    }
    for (int i = threadIdx.x; i < 2048; i += 256) {
        float d = linv[i] - linv_a[i];
        s2 += d * d;
    }
    s1 = block_sum(s1);
    s2 = block_sum(s2);
    s3 = block_sum(s3);
    if (threadIdx.x == 0) {
        float loss = g_ws[OFF_REC] / 1572864.0f + s1 / 1024.0f + 0.01f * (s2 / 2048.0f)
                   + s3 / 1024.0f;
        if (bf) ((__hip_bfloat16*)outp)[1572864] = __float2bfloat16(loss);
        else    ((float*)outp)[1572864] = loss;
    }
}

extern "C" void kernel_launch(void* const* d_in, const int* in_sizes, int n_in,
                              void* d_out, int out_size, void* d_ws, size_t ws_size,
                              hipStream_t stream) {
    const void* x     = d_in[0];
    const void* x_st  = d_in[1];
    const void* x_at  = d_in[2];
    const void* coord = d_in[3];
    const void* vec   = d_in[4];

    dim3 blk(256);

    detect_k<<<1, 64, 0, stream>>>(x);
    wconv_k<<<64, blk, 0, stream>>>(
        d_in[5],  d_in[6],  d_in[7],  d_in[8],
        d_in[9],  d_in[10], d_in[11], d_in[12],
        d_in[13], d_in[14], d_in[15], d_in[16],
        d_in[17], d_in[18], d_in[19], d_in[20]);

    // ---- round-12 launch shapes (OCG=16/8): issue-mix > occupancy (round-13 lesson) ----
    conv_s2m2_k<<<64 * 4 * 16, blk, 0, stream>>>(x_at, x_st, OFF_X1);
    conv64t_k<64, 16><<<64 * 4 * 4, blk, 0, stream>>>(OFF_X1, W_ESW2, W_ESB2, OFF_X2, 4, 64, 1);
    conv64t_k<64, 8><<<64 * 2 * 4, blk, 0, stream>>>(OFF_X2, W_ESWP, W_ESBP, OFF_PARTS, 2, 16, 0);
    sm_mom2_k<<<1024, blk, 0, stream>>>();

    // ---- e_alpha(app_sum = X2 batches 32..63 = R2) -> f_xs (C2), then alpha ----
    conv64t_k<64, 8><<<32 * 8 * 4, blk, 0, stream>>>(OFF_APPH2, W_EAW1, W_EAB1, OFF_R1, 8, 64, 1);
    conv64t_k<64, 8><<<32 * 4 * 4, blk, 0, stream>>>(OFF_R1, W_EAW2, W_EAB2, OFF_C2, 4, 32, 0);
    alpha_k<<<512, blk, 0, stream>>>(OFF_C2, OFF_PARTSA);

    // ---- encoding into R1: heat (ch 0..15, shape mu/linv) + fmap (ch 16..47) ----
    heat_k<<<512, blk, 0, stream>>>(OFF_MU, OFF_LINV, OFF_R1);
    fmap_k<<<32 * 32 * 16, blk, 0, stream>>>(OFF_R1);

    // ---- decoder: E(R1) -> D1(R2) -> D2(R3) -> out ----
    conv64t_k<48, 8><<<32 * 8 * 4, blk, 0, stream>>>(OFF_R1, W_DW1, W_DB1, OFF_R2, 8, 64, 1);
    conv_upmt_k<<<32 * 2 * 16, blk, 0, stream>>>(OFF_R2, OFF_R3);
    conv_sigmt_k<<<32 * 16, blk, 0, stream>>>(OFF_R3, x, d_out);

    // ---- loss ----
    loss_k<<<1, blk, 0, stream>>>(coord, vec, d_out);
}

// Round 16
// 560.843 us; speedup vs baseline: 2.9116x; 2.1182x over previous
//
#include <hip/hip_runtime.h>
#include <hip/hip_bf16.h>

#define EPS 1e-6f
#define SCAL 5.0f

typedef __attribute__((ext_vector_type(8))) short bf8v;   // 8 bf16 (4 VGPRs)
typedef __attribute__((ext_vector_type(4))) float f32x4;  // MFMA acc

// ---- workspace (float units) ----
#define OFF_MU     0
#define OFF_LINV   1024
#define OFF_MUA    3072
#define OFF_LINVA  4096
#define OFF_HSUM   6144
#define OFF_ALPHA  6656
#define OFF_REC    23040
#define OFF_R1     32768
#define OFF_R2     (OFF_R1 + 8388608)
#define OFF_R3     (OFF_R2 + 8388608)
#define WS_TOTAL   (OFF_R3 + 16777216)

// NHWC bf16 tensors (offsets in bf16 elements) and fp32 tensors (float offsets)
#define BA_XA   ((size_t)2 * OFF_R3)            // conv1 out [64,4096,64]
#define BA_X2   ((size_t)2 * OFF_R1)            // conv2 out [64,4096,64]
#define OFF_PARTSF OFF_R2                        // parts logits fp32 [64,4096,16]
#define OFF_PROBS  (OFF_R2 + 4194304)            // app probs fp32 [32,16,4096]
#define BA_EA1  ((size_t)2 * OFF_R3)            // ea1 out [32,4096,64]
#define OFF_FXS (OFF_R3 + 4194304)              // f_xs fp32 [32,4096,32]
#define BA_E    ((size_t)2 * OFF_R2)            // encoding [32,4096,64] (48 real + 16 pad)
#define BA_D1   ((size_t)2 * OFF_R1)            // dw1 out [32,4096,64]
#define BA_D2   ((size_t)2 * OFF_R3)            // upconv out [32,16384,32]

// g_wt fp32 layout
#define WT_ESW1 0
#define WT_ESB1 1728
#define WT_ESB2 1792
#define WT_ESBP 1856
#define WT_EAB1 1872
#define WT_EAB2 1936
#define WT_DB1  1968
#define WT_DB2  2032
#define WT_W3P  2064
#define WT_DB3  2928
// g_wp bf16 packed weights [tap][oc][ic]
#define P_WP2  0
#define P_WPP  36864
#define P_WPA1 46080
#define P_WPA2 82944
#define P_WPD1 101376
#define P_WPD2 138240

__device__ __attribute__((aligned(16))) float g_ws[WS_TOTAL];
__device__ __attribute__((aligned(16))) float g_wt[3072];
__device__ __attribute__((aligned(16))) __hip_bfloat16 g_wp[156672];
__device__ int g_isbf16;

__device__ __forceinline__ float selz(bool c, float v) { return c ? v : 0.f; }
__device__ __forceinline__ float cvtbf(short s) {
    return __uint_as_float(((unsigned int)(unsigned short)s) << 16);
}
// runtime-dtype external load (adaptive — fixed-dtype builds NaN'd in rounds 1/2/7)
__device__ __forceinline__ float ldin(const void* p, size_t i, int bf) {
    return bf ? __bfloat162float(((const __hip_bfloat16*)p)[i])
              : ((const float*)p)[i];
}

// ---------------- block reductions (blockDim.x == 256) ----------------
__device__ __forceinline__ float block_sum(float v) {
    __shared__ float sb[8];
    for (int off = 32; off; off >>= 1) v += __shfl_down(v, off, 64);
    int lane = threadIdx.x & 63, wid = threadIdx.x >> 6;
    __syncthreads();
    if (lane == 0) sb[wid] = v;
    __syncthreads();
    float r = 0.f;
    for (int i = 0; i < 4; ++i) r += sb[i];
    return r;
}
__device__ __forceinline__ float block_max(float v) {
    __shared__ float sb[8];
    for (int off = 32; off; off >>= 1) v = fmaxf(v, __shfl_down(v, off, 64));
    int lane = threadIdx.x & 63, wid = threadIdx.x >> 6;
    __syncthreads();
    if (lane == 0) sb[wid] = v;
    __syncthreads();
    float r = -1e30f;
    for (int i = 0; i < 4; ++i) r = fmaxf(r, sb[i]);
    return r;
}

// ---------------- dtype probe + init ----------------
__global__ void detect_k(const void* x) {
    const __hip_bfloat16* p = (const __hip_bfloat16*)x;
    int lane = threadIdx.x & 63;
    float v = 0.f;
    for (int i = lane; i < 256; i += 64) {
        float a = fabsf(__bfloat162float(p[i]));
        if (!(a <= 2.0f)) v = 1.f;
    }
    for (int off = 32; off; off >>= 1) v += __shfl_down(v, off, 64);
    if (lane == 0) {
        g_isbf16 = (v == 0.f) ? 1 : 0;
        g_ws[OFF_REC] = 0.f;
    }
}

// ---------------- weight pack: ext dtype -> g_wt fp32 + g_wp bf16 [t][n][k] ----------------
__global__ void wpack_k(const void* esw1, const void* esb1, const void* esw2, const void* esb2,
                        const void* eswp, const void* esbp, const void* eaw1, const void* eab1,
                        const void* eaw2, const void* eab2, const void* dw1, const void* db1,
                        const void* dw2, const void* db2, const void* dw3, const void* db3) {
    int bf = g_isbf16;
    int gid0 = blockIdx.x * 256 + threadIdx.x, stride = gridDim.x * 256;
    for (int g = gid0; g < 1728; g += stride) g_wt[WT_ESW1 + g] = ldin(esw1, g, bf);
    for (int g = gid0; g < 64; g += stride) g_wt[WT_ESB1 + g] = ldin(esb1, g, bf);
    for (int g = gid0; g < 64; g += stride) g_wt[WT_ESB2 + g] = ldin(esb2, g, bf);
    for (int g = gid0; g < 16; g += stride) g_wt[WT_ESBP + g] = ldin(esbp, g, bf);
    for (int g = gid0; g < 64; g += stride) g_wt[WT_EAB1 + g] = ldin(eab1, g, bf);
    for (int g = gid0; g < 32; g += stride) g_wt[WT_EAB2 + g] = ldin(eab2, g, bf);
    for (int g = gid0; g < 64; g += stride) g_wt[WT_DB1 + g] = ldin(db1, g, bf);
    for (int g = gid0; g < 32; g += stride) g_wt[WT_DB2 + g] = ldin(db2, g, bf);
    for (int g = gid0; g < 3; g += stride) g_wt[WT_DB3 + g] = ldin(db3, g, bf);
    for (int g = gid0; g < 864; g += stride) {              // w3p[t][o][k]
        int t = g / 96, o = (g / 32) % 3, k = g & 31;
        g_wt[WT_W3P + g] = ldin(dw3, (size_t)(o * 32 + k) * 9 + t, bf);
    }
    for (int g = gid0; g < 36864; g += stride) {            // wp2[t][n][k] from es_w2[n][k][t]
        int t = g >> 12, n = (g >> 6) & 63, k = g & 63;
        g_wp[P_WP2 + g] = __float2bfloat16(ldin(esw2, (size_t)(n * 64 + k) * 9 + t, bf));
    }
    for (int g = gid0; g < 9216; g += stride) {             // wpp[t][n<16][k]
        int t = g >> 10, n = (g >> 6) & 15, k = g & 63;
        g_wp[P_WPP + g] = __float2bfloat16(ldin(eswp, (size_t)(n * 64 + k) * 9 + t, bf));
    }
    for (int g = gid0; g < 36864; g += stride) {            // wpa1
        int t = g >> 12, n = (g >> 6) & 63, k = g & 63;
        g_wp[P_WPA1 + g] = __float2bfloat16(ldin(eaw1, (size_t)(n * 64 + k) * 9 + t, bf));
    }
    for (int g = gid0; g < 18432; g += stride) {            // wpa2[t][n<32][k]
        int t = g >> 11, n = (g >> 6) & 31, k = g & 63;
        g_wp[P_WPA2 + g] = __float2bfloat16(ldin(eaw2, (size_t)(n * 64 + k) * 9 + t, bf));
    }
    for (int g = gid0; g < 36864; g += stride) {            // wpd1: K=48 zero-padded to 64
        int t = g >> 12, n = (g >> 6) & 63, k = g & 63;
        float v = (k < 48) ? ldin(dw1, (size_t)(n * 48 + k) * 9 + t, bf) : 0.f;
        g_wp[P_WPD1 + g] = __float2bfloat16(v);
    }
    for (int g = gid0; g < 18432; g += stride) {            // wpd2[t][n<32][k]
        int t = g >> 11, n = (g >> 6) & 31, k = g & 63;
        g_wp[P_WPD2 + g] = __float2bfloat16(ldin(dw2, (size_t)(n * 64 + k) * 9 + t, bf));
    }
}

// ---------------- conv1 both streams: stride-2 -> NHWC bf16 [64,4096,64], relu ----
__global__ void __launch_bounds__(256)
conv_s2n_k(const void* __restrict__ inA, const void* __restrict__ inB) {
    int bf = g_isbf16;
    int tile = blockIdx.x & 15;
    int gb = blockIdx.x >> 4;
    int g = gb & 3, b = gb >> 2;
    const void* in = (b < 32) ? inA : inB;
    int bb = b & 31;
    int pix = tile * 256 + threadIdx.x;
    int y = pix >> 6, x = pix & 63;
    size_t inb = (size_t)bb * 3 * 16384;
    const float* W = g_wt + WT_ESW1 + (size_t)(g * 16) * 27;
    float acc[16];
    #pragma unroll
    for (int o = 0; o < 16; ++o) acc[o] = g_wt[WT_ESB1 + g * 16 + o];
    int iy0 = 2 * y, ix0 = 2 * x;
    bool my2 = (iy0 + 2 < 128), mx2 = (ix0 + 2 < 128);
    int iy2 = my2 ? iy0 + 2 : 127, ix2 = mx2 ? ix0 + 2 : 127;
    for (int ic = 0; ic < 3; ++ic) {
        size_t pb = inb + ic * 16384;
        float t[9];
        t[0] = ldin(in, pb + iy0 * 128 + ix0, bf);
        t[1] = ldin(in, pb + iy0 * 128 + ix0 + 1, bf);
        t[2] = selz(mx2, ldin(in, pb + iy0 * 128 + ix2, bf));
        t[3] = ldin(in, pb + (iy0 + 1) * 128 + ix0, bf);
        t[4] = ldin(in, pb + (iy0 + 1) * 128 + ix0 + 1, bf);
        t[5] = selz(mx2, ldin(in, pb + (iy0 + 1) * 128 + ix2, bf));
        t[6] = selz(my2, ldin(in, pb + iy2 * 128 + ix0, bf));
        t[7] = selz(my2, ldin(in, pb + iy2 * 128 + ix0 + 1, bf));
        t[8] = selz(my2 && mx2, ldin(in, pb + iy2 * 128 + ix2, bf));
        #pragma unroll
        for (int o = 0; o < 16; ++o) {
            const float* wr = W + (o * 3 + ic) * 9;
            float a = acc[o];
            #pragma unroll
            for (int j = 0; j < 9; ++j) a = fmaf(t[j], wr[j], a);
            acc[o] = a;
        }
    }
    __hip_bfloat16* out = (__hip_bfloat16*)g_ws + BA_XA + ((size_t)b * 4096 + pix) * 64 + g * 16;
    #pragma unroll
    for (int o = 0; o < 16; ++o) out[o] = __float2bfloat16(fmaxf(acc[o], 0.f));
}

// ---------------- MFMA 3x3 conv on 64x64 NHWC (Cin=64): wave = 1 row x NS*16 ocs ----------------
// A[m=lane&15][k=quad*8+j]; B[k][n=lane&15] from wp[t][n][k]; C col=lane&15 row=quad*4+reg
template<int NS, int OUTF32, int RELU>
__global__ void __launch_bounds__(256) __attribute__((amdgpu_waves_per_eu(2, 4)))
conv_mf_k(size_t in_off, int wp_off, int bias_off, size_t out_off) {
    int wid = threadIdx.x >> 6, lane = threadIdx.x & 63;
    int l15 = lane & 15, quad = lane >> 4;
    int row = blockIdx.x * 4 + wid;
    int b = row >> 6, y = row & 63;
    const __hip_bfloat16* inb = (const __hip_bfloat16*)g_ws + in_off + (size_t)b * 4096 * 64;
    f32x4 acc[4][NS];
    #pragma unroll
    for (int ms = 0; ms < 4; ++ms)
        #pragma unroll
        for (int ns = 0; ns < NS; ++ns) acc[ms][ns] = (f32x4){0.f, 0.f, 0.f, 0.f};
    #pragma unroll
    for (int t = 0; t < 9; ++t) {
        int dy = t / 3 - 1, dx = t % 3 - 1;
        int yy = y + dy;
        if (yy < 0 || yy > 63) continue;
        #pragma unroll
        for (int c = 0; c < 2; ++c) {
            bf8v a[4];
            #pragma unroll
            for (int ms = 0; ms < 4; ++ms) {
                int xx = ms * 16 + l15 + dx;
                bool v = (xx >= 0 && xx < 64);
                int xc = v ? xx : 0;
                bf8v av = *(const bf8v*)(inb + ((size_t)(yy * 64 + xc) * 64 + c * 32 + quad * 8));
                if (!v) av = (bf8v){0, 0, 0, 0, 0, 0, 0, 0};
                a[ms] = av;
            }
            #pragma unroll
            for (int ns = 0; ns < NS; ++ns) {
                bf8v bv = *(const bf8v*)(g_wp + wp_off +
                          ((size_t)(t * NS * 16 + ns * 16 + l15) * 64 + c * 32 + quad * 8));
                #pragma unroll
                for (int ms = 0; ms < 4; ++ms)
                    acc[ms][ns] = __builtin_amdgcn_mfma_f32_16x16x32_bf16(a[ms], bv, acc[ms][ns], 0, 0, 0);
            }
        }
    }
    #pragma unroll
    for (int ns = 0; ns < NS; ++ns) {
        float bias = g_wt[bias_off + ns * 16 + l15];
        #pragma unroll
        for (int ms = 0; ms < 4; ++ms) {
            #pragma unroll
            for (int r = 0; r < 4; ++r) {
                int pix = ms * 16 + quad * 4 + r;
                float v = acc[ms][ns][r] + bias;
                if (RELU) v = fmaxf(v, 0.f);
                size_t o = out_off + ((size_t)(b * 4096 + y * 64 + pix)) * (NS * 16) + ns * 16 + l15;
                if (OUTF32) g_ws[o] = v;
                else ((__hip_bfloat16*)g_ws)[o] = __float2bfloat16(v);
            }
        }
    }
}

// ---------------- MFMA decoder conv2 + 2x nearest upsample: wave = 1 out-row(128px) x 32 ocs ----
__global__ void __launch_bounds__(256) __attribute__((amdgpu_waves_per_eu(2, 4)))
conv_upmf_k(size_t in_off, int wp_off, int bias_off, size_t out_off) {
    int wid = threadIdx.x >> 6, lane = threadIdx.x & 63;
    int l15 = lane & 15, quad = lane >> 4;
    int row = blockIdx.x * 4 + wid;
    int b = row >> 7, y = row & 127;
    const __hip_bfloat16* inb = (const __hip_bfloat16*)g_ws + in_off + (size_t)b * 4096 * 64;
    f32x4 acc[8][2];
    #pragma unroll
    for (int ms = 0; ms < 8; ++ms)
        #pragma unroll
        for (int ns = 0; ns < 2; ++ns) acc[ms][ns] = (f32x4){0.f, 0.f, 0.f, 0.f};
    #pragma unroll
    for (int t = 0; t < 9; ++t) {
        int dy = t / 3 - 1, dx = t % 3 - 1;
        int yy = y + dy;
        if (yy < 0 || yy > 127) continue;
        int yi = yy >> 1;
        #pragma unroll
        for (int c = 0; c < 2; ++c) {
            bf8v a[8];
            #pragma unroll
            for (int ms = 0; ms < 8; ++ms) {
                int xx = ms * 16 + l15 + dx;
                bool v = (xx >= 0 && xx < 128);
                int xi = (v ? xx : 0) >> 1;
                bf8v av = *(const bf8v*)(inb + ((size_t)(yi * 64 + xi) * 64 + c * 32 + quad * 8));
                if (!v) av = (bf8v){0, 0, 0, 0, 0, 0, 0, 0};
                a[ms] = av;
            }
            #pragma unroll
            for (int ns = 0; ns < 2; ++ns) {
                bf8v bv = *(const bf8v*)(g_wp + wp_off +
                          ((size_t)(t * 32 + ns * 16 + l15) * 64 + c * 32 + quad * 8));
                #pragma unroll
                for (int ms = 0; ms < 8; ++ms)
                    acc[ms][ns] = __builtin_amdgcn_mfma_f32_16x16x32_bf16(a[ms], bv, acc[ms][ns], 0, 0, 0);
            }
        }
    }
    #pragma unroll
    for (int ns = 0; ns < 2; ++ns) {
        float bias = g_wt[bias_off + ns * 16 + l15];
        #pragma unroll
        for (int ms = 0; ms < 8; ++ms) {
            #pragma unroll
            for (int r = 0; r < 4; ++r) {
                int pix = ms * 16 + quad * 4 + r;
                float v = fmaxf(acc[ms][ns][r] + bias, 0.f);
                size_t o = out_off + ((size_t)(b * 16384 + y * 128 + pix)) * 32 + ns * 16 + l15;
                ((__hip_bfloat16*)g_ws)[o] = __float2bfloat16(v);
            }
        }
    }
}

// ---------------- fused softmax+moments: parts logits fp32 NHWC [64,4096,16] ----------------
__global__ void sm_mom3_k() {
    int bk = blockIdx.x;
    int b = bk >> 4, k = bk & 15;
    int app = (b >= 32);
    const float* P = g_ws + OFF_PARTSF + (size_t)b * 4096 * 16 + k;
    float r[16];
    #pragma unroll
    for (int j = 0; j < 16; ++j) r[j] = P[(size_t)(threadIdx.x + j * 256) * 16];
    float m = r[0];
    #pragma unroll
    for (int j = 1; j < 16; ++j) m = fmaxf(m, r[j]);
    m = block_max(m);
    float s = 0.f;
    #pragma unroll
    for (int j = 0; j < 16; ++j) { r[j] = __expf(r[j] - m); s += r[j]; }
    s = block_sum(s);
    float inv = 1.0f / s;
    float sy = 0, sx = 0, syy = 0, sxy = 0, sxx = 0;
    #pragma unroll
    for (int j = 0; j < 16; ++j) {
        float pv = r[j] * inv;
        int i = threadIdx.x + j * 256;
        if (app) g_ws[OFF_PROBS + ((size_t)(b - 32) * 16 + k) * 4096 + i] = pv;
        float gy = -1.0f + (i >> 6) * (2.0f / 63.0f);
        float gx = -1.0f + (i & 63) * (2.0f / 63.0f);
        sy += pv * gy; sx += pv * gx;
        syy += pv * gy * gy; sxy += pv * gy * gx; sxx += pv * gx * gx;
    }
    sy = block_sum(sy); sx = block_sum(sx);
    syy = block_sum(syy); sxy = block_sum(sxy); sxx = block_sum(sxx);
    if (threadIdx.x == 0) {
        float c00 = syy - sy * sy, c01 = sxy - sy * sx, c11 = sxx - sx * sx;
        float a = sqrtf(fmaxf(c00 + EPS, 1e-12f));
        float bb = c01 / (a + EPS);
        float cc = sqrtf(fmaxf(c11 - bb * bb, 0.f) + EPS);
        float det = a * cc;
        float sc = SCAL / (det + EPS);
        int idx = app ? ((b - 32) * 16 + k) : (b * 16 + k);
        int mu_off = app ? OFF_MUA : OFF_MU;
        int linv_off = app ? OFF_LINVA : OFF_LINV;
        g_ws[mu_off + idx * 2 + 0] = sy;
        g_ws[mu_off + idx * 2 + 1] = sx;
        g_ws[linv_off + idx * 4 + 0] = cc * sc;
        g_ws[linv_off + idx * 4 + 1] = 0.f;
        g_ws[linv_off + idx * 4 + 2] = -bb * sc;
        g_ws[linv_off + idx * 4 + 3] = a * sc;
    }
}

// ---------------- alpha[b,k,f] = sum_hw probs[b,k,hw] * fxs[b,hw,f] (both fp32) ----------------
__global__ void alpha2_k() {
    int bk = blockIdx.x;
    int b = bk >> 4;
    __shared__ float pl[4096];
    const float* pr = g_ws + OFF_PROBS + (size_t)bk * 4096;
    for (int i = threadIdx.x; i < 4096; i += 256) pl[i] = pr[i];
    __syncthreads();
    float acc[32];
    #pragma unroll
    for (int f = 0; f < 32; ++f) acc[f] = 0.f;
    for (int i = threadIdx.x; i < 4096; i += 256) {
        float pv = pl[i];
        const float* fp = g_ws + OFF_FXS + (size_t)(b * 4096 + i) * 32;
        #pragma unroll
        for (int f = 0; f < 32; ++f) acc[f] = fmaf(pv, fp[f], acc[f]);
    }
    __shared__ float sw[4][32];
    int lane = threadIdx.x & 63, wid = threadIdx.x >> 6;
    #pragma unroll
    for (int f = 0; f < 32; ++f)
        for (int off = 32; off; off >>= 1) acc[f] += __shfl_down(acc[f], off, 64);
    if (lane == 0) {
        #pragma unroll
        for (int f = 0; f < 32; ++f) sw[wid][f] = acc[f];
    }
    __syncthreads();
    if (threadIdx.x < 32)
        g_ws[OFF_ALPHA + bk * 32 + threadIdx.x] =
            sw[0][threadIdx.x] + sw[1][threadIdx.x] + sw[2][threadIdx.x] + sw[3][threadIdx.x];
}

// ---------------- heat -> E NHWC bf16 ch[0..16), + hsum ----------------
__global__ void heat2_k() {
    int bk = blockIdx.x;
    int b = bk >> 4, k = bk & 15;
    float m0 = g_ws[OFF_MU + bk * 2], m1 = g_ws[OFF_MU + bk * 2 + 1];
    float L00 = g_ws[OFF_LINV + bk * 4 + 0], L10 = g_ws[OFF_LINV + bk * 4 + 2],
          L11 = g_ws[OFF_LINV + bk * 4 + 3];
    __hip_bfloat16* E = (__hip_bfloat16*)g_ws + BA_E;
    float s = 0.f;
    for (int i = threadIdx.x; i < 4096; i += 256) {
        float d0 = -1.0f + (i >> 6) * (2.0f / 63.0f) - m0;
        float d1 = -1.0f + (i & 63) * (2.0f / 63.0f) - m1;
        float p0 = d0 * L00 + d1 * L10;
        float p1 = d1 * L11;
        float h = 1.0f / (1.0f + p0 * p0 + p1 * p1);
        E[(size_t)(b * 4096 + i) * 64 + k] = __float2bfloat16(h);
        s += h;
    }
    s = block_sum(s);
    if (threadIdx.x == 0) g_ws[OFF_HSUM + bk] = s;
}

// ---------------- fmap -> E ch[16..48), zero ch[48..64) ----------------
__global__ void fmap2_k() {
    int tile = blockIdx.x & 15, b = blockIdx.x >> 4;
    __shared__ float coef[16][32];
    for (int i = threadIdx.x; i < 512; i += 256) {
        int k = i >> 5, f = i & 31;
        coef[k][f] = g_ws[OFF_ALPHA + (b * 16 + k) * 32 + f] /
                     (g_ws[OFF_HSUM + b * 16 + k] + EPS);
    }
    __syncthreads();
    int pix = tile * 256 + threadIdx.x;
    __hip_bfloat16* E = (__hip_bfloat16*)g_ws + BA_E + (size_t)(b * 4096 + pix) * 64;
    float h[16];
    #pragma unroll
    for (int k = 0; k < 16; ++k) h[k] = __bfloat162float(E[k]);
    #pragma unroll
    for (int f = 0; f < 32; ++f) {
        float a = 0.f;
        #pragma unroll
        for (int k = 0; k < 16; ++k) a = fmaf(h[k], coef[k][f], a);
        E[16 + f] = __float2bfloat16(a);
    }
    #pragma unroll
    for (int z = 48; z < 64; ++z) E[z] = __float2bfloat16(0.f);
}

// ---------------- final conv(32->3) + sigmoid -> out, fused rec-loss; NHWC bf16 in ----------------
__global__ void __launch_bounds__(256)
conv_sign_k(const void* __restrict__ ximg, void* __restrict__ outp) {
    int bf = g_isbf16;
    int tile = blockIdx.x & 63, b = blockIdx.x >> 6;
    int pix = tile * 256 + threadIdx.x;
    int y = pix >> 7, x = pix & 127;
    const short* D2 = (const short*)((const __hip_bfloat16*)g_ws + BA_D2 + (size_t)b * 16384 * 32);
    float acc[3];
    #pragma unroll
    for (int o = 0; o < 3; ++o) acc[o] = g_wt[WT_DB3 + o];
    #pragma unroll
    for (int t = 0; t < 9; ++t) {
        int dy = t / 3 - 1, dx = t % 3 - 1;
        int yy = y + dy, xx = x + dx;
        if (yy < 0 || yy > 127 || xx < 0 || xx > 127) continue;
        const short* sp = D2 + (size_t)(yy * 128 + xx) * 32;
        #pragma unroll
        for (int c = 0; c < 4; ++c) {
            bf8v v = *(const bf8v*)(sp + c * 8);
            #pragma unroll
            for (int j = 0; j < 8; ++j) {
                float av = cvtbf(v[j]);
                int k = c * 8 + j;
                acc[0] = fmaf(av, g_wt[WT_W3P + (t * 3 + 0) * 32 + k], acc[0]);
                acc[1] = fmaf(av, g_wt[WT_W3P + (t * 3 + 1) * 32 + k], acc[1]);
                acc[2] = fmaf(av, g_wt[WT_W3P + (t * 3 + 2) * 32 + k], acc[2]);
            }
        }
    }
    float es = 0.f;
    #pragma unroll
    for (int o = 0; o < 3; ++o) {
        float v = 1.0f / (1.0f + __expf(-acc[o]));
        size_t oidx = ((size_t)b * 3 + o) * 16384 + pix;
        if (bf) ((__hip_bfloat16*)outp)[oidx] = __float2bfloat16(v);
        else    ((float*)outp)[oidx] = v;
        float e = ldin(ximg, oidx, bf) - v;
        es += e * e;
    }
    float s = block_sum(es);
    if (threadIdx.x == 0) atomicAdd(&g_ws[OFF_REC], s);
}

// ---------------- scalar loss ----------------
__global__ void loss_k(const void* __restrict__ coord,
                       const void* __restrict__ vec,
                       void* __restrict__ outp) {
    int bf = g_isbf16;
    const float* mu = g_ws + OFF_MU;
    const float* linv = g_ws + OFF_LINV;
    const float* mu_a = g_ws + OFF_MUA;
    const float* linv_a = g_ws + OFF_LINVA;
    float s1 = 0, s2 = 0, s3 = 0;
    for (int i = threadIdx.x; i < 1024; i += 256) {
        float d = mu[i] - mu_a[i];
        s1 += d * d;
        float t = ldin(coord, i, bf) + ldin(vec, i, bf);
        float d3 = mu_a[i] - t;
        s3 += d3 * d3;
    }
    for (int i = threadIdx.x; i < 2048; i += 256) {
        float d = linv[i] - linv_a[i];
        s2 += d * d;
    }
    s1 = block_sum(s1);
    s2 = block_sum(s2);
    s3 = block_sum(s3);
    if (threadIdx.x == 0) {
        float loss = g_ws[OFF_REC] / 1572864.0f + s1 / 1024.0f + 0.01f * (s2 / 2048.0f)
                   + s3 / 1024.0f;
        if (bf) ((__hip_bfloat16*)outp)[1572864] = __float2bfloat16(loss);
        else    ((float*)outp)[1572864] = loss;
    }
}

extern "C" void kernel_launch(void* const* d_in, const int* in_sizes, int n_in,
                              void* d_out, int out_size, void* d_ws, size_t ws_size,
                              hipStream_t stream) {
    const void* x     = d_in[0];
    const void* x_st  = d_in[1];
    const void* x_at  = d_in[2];
    const void* coord = d_in[3];
    const void* vec   = d_in[4];

    dim3 blk(256);

    detect_k<<<1, 64, 0, stream>>>(x);
    wpack_k<<<64, blk, 0, stream>>>(
        d_in[5],  d_in[6],  d_in[7],  d_in[8],
        d_in[9],  d_in[10], d_in[11], d_in[12],
        d_in[13], d_in[14], d_in[15], d_in[16],
        d_in[17], d_in[18], d_in[19], d_in[20]);

    // ---- encoder (B=64 batched, NHWC bf16): conv1 -> XA; conv2(MFMA) -> X2; parts(MFMA, fp32) ----
    conv_s2n_k<<<64 * 4 * 16, blk, 0, stream>>>(x_at, x_st);
    conv_mf_k<4, 0, 1><<<1024, blk, 0, stream>>>(BA_XA, P_WP2, WT_ESB2, BA_X2);
    conv_mf_k<1, 1, 0><<<1024, blk, 0, stream>>>(BA_X2, P_WPP, WT_ESBP, (size_t)OFF_PARTSF);
    sm_mom3_k<<<1024, blk, 0, stream>>>();

    // ---- e_alpha on app half -> FXS fp32; alpha ----
    conv_mf_k<4, 0, 1><<<512, blk, 0, stream>>>(BA_X2 + (size_t)32 * 4096 * 64, P_WPA1, WT_EAB1, BA_EA1);
    conv_mf_k<2, 1, 0><<<512, blk, 0, stream>>>(BA_EA1, P_WPA2, WT_EAB2, (size_t)OFF_FXS);
    alpha2_k<<<512, blk, 0, stream>>>();

    // ---- encoding E (NHWC bf16, 48+16pad): heat + fmap ----
    heat2_k<<<512, blk, 0, stream>>>();
    fmap2_k<<<512, blk, 0, stream>>>();

    // ---- decoder: dw1(MFMA) -> D1; upconv(MFMA) -> D2; sig conv -> out ----
    conv_mf_k<4, 0, 1><<<512, blk, 0, stream>>>(BA_E, P_WPD1, WT_DB1, BA_D1);
    conv_upmf_k<<<1024, blk, 0, stream>>>(BA_D1, P_WPD2, WT_DB2, BA_D2);
    conv_sign_k<<<32 * 64, blk, 0, stream>>>(x, d_out);

    // ---- loss ----
    loss_k<<<1, blk, 0, stream>>>(coord, vec, d_out);
}